// Round 1
// baseline (4105.226 us; speedup 1.0000x reference)
//
#include <hip/hip_runtime.h>

namespace {

constexpr int NP   = 19712;   // padded tokens (Nystrom)
constexpr int NT   = 19601;   // tokens incl cls
constexpr int NPIX = 19600;   // feature tokens (140x140)
constexpr int HD   = 512;     // hidden dim
constexpr int ID   = 1024;    // input dim
constexpr int NH   = 8;       // heads
constexpr int DH   = 8;       // dim per head
constexpr int NL   = 256;     // landmarks
constexpr int PADR = 111;     // left zero-pad rows
constexpr int SIDE = 140;

#define F4MAD(a, s, v) { (a).x += (s)*(v).x; (a).y += (s)*(v).y; (a).z += (s)*(v).z; (a).w += (s)*(v).w; }
#define F4SCALE(a, s)  { (a).x *= (s); (a).y *= (s); (a).z *= (s); (a).w *= (s); }

// ------------------------------------------------------------------
// fc1: out[1+m][n] = gelu(x[m] @ W[:,n] + b[n]);  M=19600 K=1024 N=512
// 64x64 tile, 256 threads, 4x4 per thread, LDS [k][i] layout for b128 reads
// ------------------------------------------------------------------
__global__ void gemm_fc1(const float* __restrict__ X, const float* __restrict__ W,
                         const float* __restrict__ bias, float* __restrict__ out)
{
    __shared__ __align__(16) float As[16][68];
    __shared__ __align__(16) float Bs[16][68];
    const int tid = threadIdx.x;
    const int tx = tid & 15, ty = tid >> 4;
    const int row0 = blockIdx.x * 64;
    const int col0 = blockIdx.y * 64;
    float acc[4][4] = {};
    const int ai = tid >> 2;            // 0..63 (row within tile)
    const int ak = (tid & 3) * 4;       // 0,4,8,12
    const int bk = tid >> 4;            // 0..15
    const int bj = (tid & 15) * 4;      // 0..60
    for (int k0 = 0; k0 < ID; k0 += 16) {
        float4 av = make_float4(0.f, 0.f, 0.f, 0.f);
        int gr = row0 + ai;
        if (gr < NPIX) av = *(const float4*)&X[(size_t)gr * ID + k0 + ak];
        As[ak + 0][ai] = av.x; As[ak + 1][ai] = av.y;
        As[ak + 2][ai] = av.z; As[ak + 3][ai] = av.w;
        *(float4*)&Bs[bk][bj] = *(const float4*)&W[(size_t)(k0 + bk) * HD + col0 + bj];
        __syncthreads();
        #pragma unroll
        for (int k = 0; k < 16; ++k) {
            float4 a = *(const float4*)&As[k][ty * 4];
            float4 b = *(const float4*)&Bs[k][tx * 4];
            acc[0][0] += a.x * b.x; acc[0][1] += a.x * b.y; acc[0][2] += a.x * b.z; acc[0][3] += a.x * b.w;
            acc[1][0] += a.y * b.x; acc[1][1] += a.y * b.y; acc[1][2] += a.y * b.z; acc[1][3] += a.y * b.w;
            acc[2][0] += a.z * b.x; acc[2][1] += a.z * b.y; acc[2][2] += a.z * b.z; acc[2][3] += a.z * b.w;
            acc[3][0] += a.w * b.x; acc[3][1] += a.w * b.y; acc[3][2] += a.w * b.z; acc[3][3] += a.w * b.w;
        }
        __syncthreads();
    }
    #pragma unroll
    for (int r = 0; r < 4; ++r) {
        int gr = row0 + ty * 4 + r;
        if (gr >= NPIX) continue;
        #pragma unroll
        for (int c = 0; c < 4; ++c) {
            int gc = col0 + tx * 4 + c;
            float v = acc[r][c] + bias[gc];
            v = 0.5f * v * (1.f + erff(v * 0.70710678118654752f));
            out[(size_t)(gr + 1) * HD + gc] = v;
        }
    }
}

__global__ void cls_init(const float* __restrict__ cls, float* __restrict__ h)
{
    int t = blockIdx.x * 256 + threadIdx.x;
    if (t < HD) h[t] = cls[t];
}

// ------------------------------------------------------------------
// layernorm rows of h (19601x512) into xp (19712x512), first 111 rows zero
// ------------------------------------------------------------------
__global__ void ln_pad(const float* __restrict__ h, const float* __restrict__ g,
                       const float* __restrict__ b, float* __restrict__ xp)
{
    const int row = blockIdx.x;
    const int tid = threadIdx.x;
    float* dst = xp + (size_t)row * HD;
    if (row < PADR) { dst[tid] = 0.f; dst[tid + 256] = 0.f; return; }
    const float* src = h + (size_t)(row - PADR) * HD;
    float v0 = src[tid], v1 = src[tid + 256];
    __shared__ float red[256];
    red[tid] = v0 + v1;
    __syncthreads();
    for (int off = 128; off > 0; off >>= 1) {
        if (tid < off) red[tid] += red[tid + off];
        __syncthreads();
    }
    float mu = red[0] * (1.f / HD);
    __syncthreads();
    float d0 = v0 - mu, d1 = v1 - mu;
    red[tid] = d0 * d0 + d1 * d1;
    __syncthreads();
    for (int off = 128; off > 0; off >>= 1) {
        if (tid < off) red[tid] += red[tid + off];
        __syncthreads();
    }
    float inv = rsqrtf(red[0] * (1.f / HD) + 1e-5f);
    dst[tid]       = d0 * inv * g[tid] + b[tid];
    dst[tid + 256] = d1 * inv * g[tid + 256] + b[tid + 256];
}

// ------------------------------------------------------------------
// qkv GEMM: xp(19712x512) @ W(512x192) -> head-split qh/kh/vh [h][t][d]
// q pre-scaled by DIM_HEAD^-0.5.  grid (308, 3)
// ------------------------------------------------------------------
__global__ void gemm_qkv(const float* __restrict__ Xp, const float* __restrict__ W,
                         float* __restrict__ qh, float* __restrict__ kh, float* __restrict__ vh)
{
    __shared__ __align__(16) float As[16][68];
    __shared__ __align__(16) float Bs[16][68];
    const int tid = threadIdx.x;
    const int tx = tid & 15, ty = tid >> 4;
    const int row0 = blockIdx.x * 64;
    const int col0 = blockIdx.y * 64;
    float acc[4][4] = {};
    const int ai = tid >> 2;
    const int ak = (tid & 3) * 4;
    const int bk = tid >> 4;
    const int bj = (tid & 15) * 4;
    for (int k0 = 0; k0 < HD; k0 += 16) {
        float4 av = *(const float4*)&Xp[(size_t)(row0 + ai) * HD + k0 + ak];
        As[ak + 0][ai] = av.x; As[ak + 1][ai] = av.y;
        As[ak + 2][ai] = av.z; As[ak + 3][ai] = av.w;
        *(float4*)&Bs[bk][bj] = *(const float4*)&W[(size_t)(k0 + bk) * 192 + col0 + bj];
        __syncthreads();
        #pragma unroll
        for (int k = 0; k < 16; ++k) {
            float4 a = *(const float4*)&As[k][ty * 4];
            float4 b = *(const float4*)&Bs[k][tx * 4];
            acc[0][0] += a.x * b.x; acc[0][1] += a.x * b.y; acc[0][2] += a.x * b.z; acc[0][3] += a.x * b.w;
            acc[1][0] += a.y * b.x; acc[1][1] += a.y * b.y; acc[1][2] += a.y * b.z; acc[1][3] += a.y * b.w;
            acc[2][0] += a.z * b.x; acc[2][1] += a.z * b.y; acc[2][2] += a.z * b.z; acc[2][3] += a.z * b.w;
            acc[3][0] += a.w * b.x; acc[3][1] += a.w * b.y; acc[3][2] += a.w * b.z; acc[3][3] += a.w * b.w;
        }
        __syncthreads();
    }
    float* dst; float scale;
    if (blockIdx.y == 0)      { dst = qh; scale = 0.35355339059327373f; }
    else if (blockIdx.y == 1) { dst = kh; scale = 1.f; }
    else                      { dst = vh; scale = 1.f; }
    #pragma unroll
    for (int r = 0; r < 4; ++r) {
        int gr = row0 + ty * 4 + r;
        #pragma unroll
        for (int c = 0; c < 4; ++c) {
            int lc = tx * 4 + c;          // 0..63 within q/k/v block
            int hh = lc >> 3, d = lc & 7;
            dst[((size_t)hh * NP + gr) * DH + d] = acc[r][c] * scale;
        }
    }
}

// ------------------------------------------------------------------
// landmark means: ql/kl[h][i][d] = mean_{j<77} qh/kh[h][i*77+j][d]
// ------------------------------------------------------------------
__global__ void landmarks(const float* __restrict__ qh, const float* __restrict__ kh,
                          float* __restrict__ ql, float* __restrict__ kl)
{
    int idx = blockIdx.x * 256 + threadIdx.x;   // 0..32767
    int sel = idx >> 14;
    int rem = idx & 16383;
    int h = rem >> 11;
    int i = (rem >> 3) & 255;
    int d = rem & 7;
    const float* src = sel ? kh : qh;
    size_t base = ((size_t)h * NP + (size_t)i * 77) * DH + d;
    float s = 0.f;
    for (int j = 0; j < 77; ++j) s += src[base + (size_t)j * DH];
    (sel ? kl : ql)[((size_t)h * NL + i) * DH + d] = s * (1.f / 77.f);
}

// ------------------------------------------------------------------
// attn2 = softmax(q_l @ k_l^T) per row; block = one (h,i) row of 256
// ------------------------------------------------------------------
__global__ void attn2_softmax(const float* __restrict__ ql, const float* __restrict__ kl,
                              float* __restrict__ a)
{
    const int i = blockIdx.x, h = blockIdx.y, j = threadIdx.x;
    __shared__ float sq[8];
    __shared__ float red[256];
    if (j < 8) sq[j] = ql[((size_t)h * NL + i) * DH + j];
    __syncthreads();
    const float* kr = kl + ((size_t)h * NL + j) * DH;
    float s = 0.f;
    #pragma unroll
    for (int d = 0; d < 8; ++d) s += sq[d] * kr[d];
    red[j] = s;
    __syncthreads();
    for (int off = 128; off > 0; off >>= 1) {
        if (j < off) red[j] = fmaxf(red[j], red[j + off]);
        __syncthreads();
    }
    float mx = red[0];
    __syncthreads();
    float e = expf(s - mx);
    red[j] = e;
    __syncthreads();
    for (int off = 128; off > 0; off >>= 1) {
        if (j < off) red[j] += red[j + off];
        __syncthreads();
    }
    a[((size_t)h * NL + i) * NL + j] = e / red[0];
}

// ------------------------------------------------------------------
// pinv init scale: part[0..7]=rowsum-max per head, part[8..15]=colsum-max
// ------------------------------------------------------------------
__global__ void pinv_norms(const float* __restrict__ a, float* __restrict__ part)
{
    const int h = blockIdx.x & 7;
    const int mode = blockIdx.x >> 3;
    const int tid = threadIdx.x;
    const float* ah = a + (size_t)h * NL * NL;
    float s = 0.f;
    if (mode == 0) { for (int j = 0; j < NL; ++j) s += fabsf(ah[tid * NL + j]); }
    else           { for (int i = 0; i < NL; ++i) s += fabsf(ah[i * NL + tid]); }
    __shared__ float red[256];
    red[tid] = s;
    __syncthreads();
    for (int off = 128; off > 0; off >>= 1) {
        if (tid < off) red[tid] = fmaxf(red[tid], red[tid + off]);
        __syncthreads();
    }
    if (tid == 0) part[mode * 8 + h] = red[0];
}

__global__ void z0_init(const float* __restrict__ a, const float* __restrict__ part,
                        float* __restrict__ z)
{
    float s1 = part[0], s2 = part[8];
    #pragma unroll
    for (int h = 1; h < 8; ++h) { s1 = fmaxf(s1, part[h]); s2 = fmaxf(s2, part[8 + h]); }
    float inv = 1.f / (s1 * s2);
    int idx = blockIdx.x * 256 + threadIdx.x;
    int h = idx >> 16;
    int rem = idx & 65535;
    int i = rem >> 8, j = rem & 255;
    z[idx] = a[((size_t)h * NL + j) * NL + i] * inv;
}

// ------------------------------------------------------------------
// batched 256x256x256: D = alpha*(A@B) + beta*A   grid (4,4,8)
// ------------------------------------------------------------------
__global__ void mm256(const float* __restrict__ A, const float* __restrict__ B,
                      float* __restrict__ D, float alpha, float beta)
{
    const int h = blockIdx.z;
    const float* Ah = A + (size_t)h * NL * NL;
    const float* Bh = B + (size_t)h * NL * NL;
    float* Dh = D + (size_t)h * NL * NL;
    __shared__ __align__(16) float As[16][68];
    __shared__ __align__(16) float Bs[16][68];
    const int tid = threadIdx.x;
    const int tx = tid & 15, ty = tid >> 4;
    const int row0 = blockIdx.x * 64;
    const int col0 = blockIdx.y * 64;
    float acc[4][4] = {};
    const int ai = tid >> 2;
    const int ak = (tid & 3) * 4;
    const int bk = tid >> 4;
    const int bj = (tid & 15) * 4;
    for (int k0 = 0; k0 < NL; k0 += 16) {
        float4 av = *(const float4*)&Ah[(size_t)(row0 + ai) * NL + k0 + ak];
        As[ak + 0][ai] = av.x; As[ak + 1][ai] = av.y;
        As[ak + 2][ai] = av.z; As[ak + 3][ai] = av.w;
        *(float4*)&Bs[bk][bj] = *(const float4*)&Bh[(size_t)(k0 + bk) * NL + col0 + bj];
        __syncthreads();
        #pragma unroll
        for (int k = 0; k < 16; ++k) {
            float4 a = *(const float4*)&As[k][ty * 4];
            float4 b = *(const float4*)&Bs[k][tx * 4];
            acc[0][0] += a.x * b.x; acc[0][1] += a.x * b.y; acc[0][2] += a.x * b.z; acc[0][3] += a.x * b.w;
            acc[1][0] += a.y * b.x; acc[1][1] += a.y * b.y; acc[1][2] += a.y * b.z; acc[1][3] += a.y * b.w;
            acc[2][0] += a.z * b.x; acc[2][1] += a.z * b.y; acc[2][2] += a.z * b.z; acc[2][3] += a.z * b.w;
            acc[3][0] += a.w * b.x; acc[3][1] += a.w * b.y; acc[3][2] += a.w * b.z; acc[3][3] += a.w * b.w;
        }
        __syncthreads();
    }
    #pragma unroll
    for (int r = 0; r < 4; ++r) {
        int gr = row0 + ty * 4 + r;
        #pragma unroll
        for (int c = 0; c < 4; ++c) {
            int gc = col0 + tx * 4 + c;
            Dh[(size_t)gr * NL + gc] = alpha * acc[r][c] + beta * Ah[(size_t)gr * NL + gc];
        }
    }
}

// ------------------------------------------------------------------
// w[h][i][:] = softmax_t(q_l[h,i]·k[h,t]) @ v  — online softmax, one pass
// block = one (i,h); 256 threads stride tokens
// ------------------------------------------------------------------
__global__ void attn3v(const float* __restrict__ kh, const float* __restrict__ vh,
                       const float* __restrict__ ql, float* __restrict__ wbuf)
{
    const int i = blockIdx.x, h = blockIdx.y, tid = threadIdx.x;
    __shared__ float sq[8];
    __shared__ float red[256];
    __shared__ float wpart[4][9];
    if (tid < 8) sq[tid] = ql[((size_t)h * NL + i) * DH + tid];
    __syncthreads();
    float4 q0 = *(const float4*)&sq[0];
    float4 q1 = *(const float4*)&sq[4];
    const float* kb = kh + (size_t)h * NP * DH;
    const float* vb = vh + (size_t)h * NP * DH;
    float m = -1e30f, den = 0.f;
    float4 acc0 = make_float4(0.f, 0.f, 0.f, 0.f);
    float4 acc1 = make_float4(0.f, 0.f, 0.f, 0.f);
    for (int t = tid; t < NP; t += 256) {
        const float4 k0 = *(const float4*)&kb[(size_t)t * 8];
        const float4 k1 = *(const float4*)&kb[(size_t)t * 8 + 4];
        float s = q0.x * k0.x + q0.y * k0.y + q0.z * k0.z + q0.w * k0.w
                + q1.x * k1.x + q1.y * k1.y + q1.z * k1.z + q1.w * k1.w;
        if (s > m) {
            float c = expf(m - s);
            den *= c; F4SCALE(acc0, c); F4SCALE(acc1, c);
            m = s;
        }
        float e = expf(s - m);
        den += e;
        const float4 v0 = *(const float4*)&vb[(size_t)t * 8];
        const float4 v1 = *(const float4*)&vb[(size_t)t * 8 + 4];
        F4MAD(acc0, e, v0); F4MAD(acc1, e, v1);
    }
    // global max
    red[tid] = m;
    __syncthreads();
    for (int off = 128; off > 0; off >>= 1) {
        if (tid < off) red[tid] = fmaxf(red[tid], red[tid + off]);
        __syncthreads();
    }
    float M = red[0];
    float f = expf(m - M);
    den *= f; F4SCALE(acc0, f); F4SCALE(acc1, f);
    // wave reduce den + acc
    float acc[8] = {acc0.x, acc0.y, acc0.z, acc0.w, acc1.x, acc1.y, acc1.z, acc1.w};
    #pragma unroll
    for (int off = 32; off > 0; off >>= 1) {
        den += __shfl_down(den, off);
        #pragma unroll
        for (int d = 0; d < 8; ++d) acc[d] += __shfl_down(acc[d], off);
    }
    const int wave = tid >> 6, lane = tid & 63;
    if (lane == 0) {
        wpart[wave][0] = den;
        #pragma unroll
        for (int d = 0; d < 8; ++d) wpart[wave][1 + d] = acc[d];
    }
    __syncthreads();
    if (tid < 9) red[tid] = wpart[0][tid] + wpart[1][tid] + wpart[2][tid] + wpart[3][tid];
    __syncthreads();
    if (tid < 8) wbuf[((size_t)h * NL + i) * DH + tid] = red[1 + tid] / red[0];
}

// ------------------------------------------------------------------
// zw[h][i][d] = sum_j z[h][i][j] * w[h][j][d]
// ------------------------------------------------------------------
__global__ void zw_mul(const float* __restrict__ z, const float* __restrict__ w,
                       float* __restrict__ zw)
{
    int idx = blockIdx.x * 256 + threadIdx.x;   // 16384
    int h = idx >> 11;
    int rem = idx & 2047;
    int i = rem >> 3, d = rem & 7;
    const float* zr = z + ((size_t)h * NL + i) * NL;
    const float* wb = w + (size_t)h * NL * DH + d;
    float s = 0.f;
    for (int j = 0; j < NL; ++j) s += zr[j] * wb[(size_t)j * DH];
    zw[idx] = s;
}

// ------------------------------------------------------------------
// attn1 fused: out[r][h*8+d] = softmax_i(q[h,t]·k_l[h,i]) @ zw[h,i,d] + dwconv33(v)
// t = r + 111; online softmax over 256 landmarks held in LDS
// ------------------------------------------------------------------
__global__ void attn1_conv(const float* __restrict__ qh, const float* __restrict__ vh,
                           const float* __restrict__ klg, const float* __restrict__ zwg,
                           const float* __restrict__ rw, float* __restrict__ aout)
{
    const int h = blockIdx.y;
    __shared__ __align__(16) float kl[NL * DH];
    __shared__ __align__(16) float zw[NL * DH];
    const int tid = threadIdx.x;
    for (int q = tid; q < NL * DH; q += 256) {
        kl[q] = klg[(size_t)h * NL * DH + q];
        zw[q] = zwg[(size_t)h * NL * DH + q];
    }
    __syncthreads();
    const int r = blockIdx.x * 256 + tid;
    if (r >= NT) return;
    const int t = r + PADR;
    const float* qp = qh + ((size_t)h * NP + t) * DH;
    float4 q0 = *(const float4*)qp;
    float4 q1 = *(const float4*)(qp + 4);
    float m = -1e30f, den = 0.f;
    float4 acc0 = make_float4(0.f, 0.f, 0.f, 0.f);
    float4 acc1 = make_float4(0.f, 0.f, 0.f, 0.f);
    for (int i = 0; i < NL; ++i) {
        float4 k0 = *(const float4*)&kl[i * 8];
        float4 k1 = *(const float4*)&kl[i * 8 + 4];
        float s = q0.x * k0.x + q0.y * k0.y + q0.z * k0.z + q0.w * k0.w
                + q1.x * k1.x + q1.y * k1.y + q1.z * k1.z + q1.w * k1.w;
        if (s > m) {
            float c = expf(m - s);
            den *= c; F4SCALE(acc0, c); F4SCALE(acc1, c);
            m = s;
        }
        float e = expf(s - m);
        den += e;
        float4 z0 = *(const float4*)&zw[i * 8];
        float4 z1 = *(const float4*)&zw[i * 8 + 4];
        F4MAD(acc0, e, z0); F4MAD(acc1, e, z1);
    }
    float inv = 1.f / den;
    F4SCALE(acc0, inv); F4SCALE(acc1, inv);
    // depthwise conv along tokens, kernel 33, pad 16
    const float* vb = vh + (size_t)h * NP * DH;
    #pragma unroll
    for (int j = 0; j < 33; ++j) {
        int tp = t - 16 + j;          // >= 95 always
        if (tp >= NP) continue;
        float wv = rw[h * 33 + j];
        float4 v0 = *(const float4*)&vb[(size_t)tp * 8];
        float4 v1 = *(const float4*)&vb[(size_t)tp * 8 + 4];
        F4MAD(acc0, wv, v0); F4MAD(acc1, wv, v1);
    }
    float* op = aout + (size_t)r * 64 + h * 8;
    *(float4*)op = acc0;
    *(float4*)(op + 4) = acc1;
}

// ------------------------------------------------------------------
// out-proj + residual: h[r] += aout[r] @ W(64x512) + b ;  8 rows/block
// ------------------------------------------------------------------
__global__ void outproj(const float* __restrict__ aout, const float* __restrict__ W,
                        const float* __restrict__ bias, float* __restrict__ h)
{
    const int r0 = blockIdx.x * 8;
    const int tid = threadIdx.x;   // 512
    __shared__ float ao[8][64];
    {
        int rr = tid >> 6, kk = tid & 63;
        int gr = r0 + rr;
        ao[rr][kk] = (gr < NT) ? aout[(size_t)gr * 64 + kk] : 0.f;
    }
    __syncthreads();
    float acc[8] = {};
    for (int k = 0; k < 64; ++k) {
        float wv = W[(size_t)k * HD + tid];
        #pragma unroll
        for (int r = 0; r < 8; ++r) acc[r] += ao[r][k] * wv;
    }
    float bv = bias[tid];
    #pragma unroll
    for (int r = 0; r < 8; ++r) {
        int gr = r0 + r;
        if (gr < NT) h[(size_t)gr * HD + tid] += acc[r] + bv;
    }
}

// ------------------------------------------------------------------
// PPEG: combined 7x7+5x5+3x3 depthwise stencil + identity; cls copied
// grid (19601, 2) — blockIdx.x==19600 handles cls row
// ------------------------------------------------------------------
__global__ void ppeg_kernel(const float* __restrict__ hin,
                            const float* __restrict__ w7, const float* __restrict__ b7,
                            const float* __restrict__ w5, const float* __restrict__ b5,
                            const float* __restrict__ w3, const float* __restrict__ b3,
                            float* __restrict__ hout)
{
    const int c = blockIdx.y * 256 + threadIdx.x;
    const int p = blockIdx.x;
    if (p == NPIX) { hout[c] = hin[c]; return; }
    const int y = p / SIDE, x = p - y * SIDE;
    float accv = hin[(size_t)(1 + p) * HD + c] + b7[c] + b5[c] + b3[c];
    const float* w7c = w7 + (size_t)c * 49;
    const float* w5c = w5 + (size_t)c * 25;
    const float* w3c = w3 + (size_t)c * 9;
    for (int dy = -3; dy <= 3; ++dy) {
        int yy = y + dy;
        if (yy < 0 || yy >= SIDE) continue;
        for (int dx = -3; dx <= 3; ++dx) {
            int xx = x + dx;
            if (xx < 0 || xx >= SIDE) continue;
            float wv = w7c[(dy + 3) * 7 + (dx + 3)];
            if (dy >= -2 && dy <= 2 && dx >= -2 && dx <= 2) wv += w5c[(dy + 2) * 5 + (dx + 2)];
            if (dy >= -1 && dy <= 1 && dx >= -1 && dx <= 1) wv += w3c[(dy + 1) * 3 + (dx + 1)];
            accv += wv * hin[(size_t)(1 + yy * SIDE + xx) * HD + c];
        }
    }
    hout[(size_t)(1 + p) * HD + c] = accv;
}

// ------------------------------------------------------------------
// final layernorm of row 0 -> d_out (512 floats)
// ------------------------------------------------------------------
__global__ void final_ln(const float* __restrict__ h, const float* __restrict__ g,
                         const float* __restrict__ b, float* __restrict__ out)
{
    const int tid = threadIdx.x;
    float v0 = h[tid], v1 = h[tid + 256];
    __shared__ float red[256];
    red[tid] = v0 + v1;
    __syncthreads();
    for (int off = 128; off > 0; off >>= 1) {
        if (tid < off) red[tid] += red[tid + off];
        __syncthreads();
    }
    float mu = red[0] * (1.f / HD);
    __syncthreads();
    float d0 = v0 - mu, d1 = v1 - mu;
    red[tid] = d0 * d0 + d1 * d1;
    __syncthreads();
    for (int off = 128; off > 0; off >>= 1) {
        if (tid < off) red[tid] += red[tid + off];
        __syncthreads();
    }
    float inv = rsqrtf(red[0] * (1.f / HD) + 1e-5f);
    out[tid]       = d0 * inv * g[tid] + b[tid];
    out[tid + 256] = d1 * inv * g[tid + 256] + b[tid + 256];
}

} // namespace

extern "C" void kernel_launch(void* const* d_in, const int* in_sizes, int n_in,
                              void* d_out, int out_size, void* d_ws, size_t ws_size,
                              hipStream_t stream)
{
    const float* x      = (const float*)d_in[0];
    const float* fc1_w  = (const float*)d_in[1];
    const float* fc1_b  = (const float*)d_in[2];
    const float* cls    = (const float*)d_in[3];
    const float* l1_g   = (const float*)d_in[4];
    const float* l1_bb  = (const float*)d_in[5];
    const float* l1_qkv = (const float*)d_in[6];
    const float* l1_ow  = (const float*)d_in[7];
    const float* l1_ob  = (const float*)d_in[8];
    const float* l1_rw  = (const float*)d_in[9];
    const float* l2_g   = (const float*)d_in[10];
    const float* l2_bb  = (const float*)d_in[11];
    const float* l2_qkv = (const float*)d_in[12];
    const float* l2_ow  = (const float*)d_in[13];
    const float* l2_ob  = (const float*)d_in[14];
    const float* l2_rw  = (const float*)d_in[15];
    const float* p7w    = (const float*)d_in[16];
    const float* p7b    = (const float*)d_in[17];
    const float* p5w    = (const float*)d_in[18];
    const float* p5b    = (const float*)d_in[19];
    const float* p3w    = (const float*)d_in[20];
    const float* p3b    = (const float*)d_in[21];
    const float* ng     = (const float*)d_in[22];
    const float* nb     = (const float*)d_in[23];
    float* out = (float*)d_out;

    char* ws = (char*)d_ws;
    size_t off = 0;
    auto alloc = [&](size_t bytes) {
        char* p = ws + off;
        off += (bytes + 255) & ~(size_t)255;
        return (float*)p;
    };
    float* bufA = alloc((size_t)NP * HD * 4);            // h (layer1) / xp (layer2)
    float* bufB = alloc((size_t)NP * HD * 4);            // xp (layer1) / h (post-ppeg)
    float* qh   = alloc((size_t)NH * NP * DH * 4);
    float* kh   = alloc((size_t)NH * NP * DH * 4);
    float* vh   = alloc((size_t)NH * NP * DH * 4);
    float* aout = alloc((size_t)NP * 64 * 4);
    float* ql   = alloc((size_t)NH * NL * DH * 4);
    float* klm  = alloc((size_t)NH * NL * DH * 4);
    float* wbuf = alloc((size_t)NH * NL * DH * 4);
    float* zwb  = alloc((size_t)NH * NL * DH * 4);
    float* a2   = alloc((size_t)NH * NL * NL * 4);
    float* zb0  = alloc((size_t)NH * NL * NL * 4);
    float* zb1  = alloc((size_t)NH * NL * NL * 4);
    float* azb  = alloc((size_t)NH * NL * NL * 4);
    float* tb   = alloc((size_t)NH * NL * NL * 4);
    float* ub   = alloc((size_t)NH * NL * NL * 4);
    float* part = alloc(256);
    (void)ws_size; (void)in_sizes; (void)n_in; (void)out_size;

    // stage 1: fc1 + gelu into bufA rows 1..19600, cls row 0
    gemm_fc1<<<dim3(307, 8), 256, 0, stream>>>(x, fc1_w, fc1_b, bufA);
    cls_init<<<2, 256, 0, stream>>>(cls, bufA);

    auto attention = [&](float* hbuf, float* xp, const float* lg, const float* lb,
                         const float* qkvw, const float* ow, const float* ob,
                         const float* rw) {
        ln_pad<<<NP, 256, 0, stream>>>(hbuf, lg, lb, xp);
        gemm_qkv<<<dim3(NP / 64, 3), 256, 0, stream>>>(xp, qkvw, qh, kh, vh);
        landmarks<<<128, 256, 0, stream>>>(qh, kh, ql, klm);
        attn2_softmax<<<dim3(NL, NH), 256, 0, stream>>>(ql, klm, a2);
        pinv_norms<<<16, 256, 0, stream>>>(a2, part);
        z0_init<<<2048, 256, 0, stream>>>(a2, part, zb0);
        float* zc = zb0;
        float* zn = zb1;
        for (int it = 0; it < 6; ++it) {
            mm256<<<dim3(4, 4, 8), 256, 0, stream>>>(a2, zc, azb, 1.f, 0.f);     // az = a@z
            mm256<<<dim3(4, 4, 8), 256, 0, stream>>>(azb, azb, tb, -1.f, 7.f);   // t = az@(7I-az)
            mm256<<<dim3(4, 4, 8), 256, 0, stream>>>(azb, tb, ub, -1.f, 15.f);   // u = az@(15I-t)
            mm256<<<dim3(4, 4, 8), 256, 0, stream>>>(zc, ub, zn, -0.25f, 3.25f); // z' = 0.25 z@(13I-u)
            float* tmp = zc; zc = zn; zn = tmp;
        }
        attn3v<<<dim3(NL, NH), 256, 0, stream>>>(kh, vh, ql, wbuf);
        zw_mul<<<64, 256, 0, stream>>>(zc, wbuf, zwb);
        attn1_conv<<<dim3(77, NH), 256, 0, stream>>>(qh, vh, klm, zwb, rw, aout);
        outproj<<<(NT + 7) / 8, 512, 0, stream>>>(aout, ow, ob, hbuf);
    };

    // layer 1 attention (residual add into bufA)
    attention(bufA, bufB, l1_g, l1_bb, l1_qkv, l1_ow, l1_ob, l1_rw);
    // PPEG: bufA -> bufB
    ppeg_kernel<<<dim3(NT, 2), 256, 0, stream>>>(bufA, p7w, p7b, p5w, p5b, p3w, p3b, bufB);
    // layer 2 attention (residual add into bufB), xp reuses bufA
    attention(bufB, bufA, l2_g, l2_bb, l2_qkv, l2_ow, l2_ob, l2_rw);
    // final layernorm of cls row
    final_ln<<<1, 256, 0, stream>>>(bufB, ng, nb, out);
}

// Round 2
// 2043.637 us; speedup vs baseline: 2.0088x; 2.0088x over previous
//
#include <hip/hip_runtime.h>

namespace {

constexpr int NP   = 19712;   // padded tokens (Nystrom)
constexpr int NT   = 19601;   // tokens incl cls
constexpr int NPIX = 19600;   // feature tokens (140x140)
constexpr int HD   = 512;     // hidden dim
constexpr int ID   = 1024;    // input dim
constexpr int NH   = 8;       // heads
constexpr int DH   = 8;       // dim per head
constexpr int NL   = 256;     // landmarks
constexpr int PADR = 111;     // left zero-pad rows
constexpr int SIDE = 140;
constexpr int CCH  = 128;     // ppeg channel chunk
constexpr int PW   = 148;     // padded image row stride (floats)
constexpr int PR   = 146;     // padded image rows

#define F4MAD(a, s, v) { (a).x += (s)*(v).x; (a).y += (s)*(v).y; (a).z += (s)*(v).z; (a).w += (s)*(v).w; }
#define F4SCALE(a, s)  { (a).x *= (s); (a).y *= (s); (a).z *= (s); (a).w *= (s); }

// ------------------------------------------------------------------
// fc1: out[1+m][n] = gelu(x[m] @ W[:,n] + b[n]);  M=19600 K=1024 N=512
// ------------------------------------------------------------------
__global__ void gemm_fc1(const float* __restrict__ X, const float* __restrict__ W,
                         const float* __restrict__ bias, float* __restrict__ out)
{
    __shared__ __align__(16) float As[16][68];
    __shared__ __align__(16) float Bs[16][68];
    const int tid = threadIdx.x;
    const int tx = tid & 15, ty = tid >> 4;
    const int row0 = blockIdx.x * 64;
    const int col0 = blockIdx.y * 64;
    float acc[4][4] = {};
    const int ai = tid >> 2;
    const int ak = (tid & 3) * 4;
    const int bk = tid >> 4;
    const int bj = (tid & 15) * 4;
    for (int k0 = 0; k0 < ID; k0 += 16) {
        float4 av = make_float4(0.f, 0.f, 0.f, 0.f);
        int gr = row0 + ai;
        if (gr < NPIX) av = *(const float4*)&X[(size_t)gr * ID + k0 + ak];
        As[ak + 0][ai] = av.x; As[ak + 1][ai] = av.y;
        As[ak + 2][ai] = av.z; As[ak + 3][ai] = av.w;
        *(float4*)&Bs[bk][bj] = *(const float4*)&W[(size_t)(k0 + bk) * HD + col0 + bj];
        __syncthreads();
        #pragma unroll
        for (int k = 0; k < 16; ++k) {
            float4 a = *(const float4*)&As[k][ty * 4];
            float4 b = *(const float4*)&Bs[k][tx * 4];
            acc[0][0] += a.x * b.x; acc[0][1] += a.x * b.y; acc[0][2] += a.x * b.z; acc[0][3] += a.x * b.w;
            acc[1][0] += a.y * b.x; acc[1][1] += a.y * b.y; acc[1][2] += a.y * b.z; acc[1][3] += a.y * b.w;
            acc[2][0] += a.z * b.x; acc[2][1] += a.z * b.y; acc[2][2] += a.z * b.z; acc[2][3] += a.z * b.w;
            acc[3][0] += a.w * b.x; acc[3][1] += a.w * b.y; acc[3][2] += a.w * b.z; acc[3][3] += a.w * b.w;
        }
        __syncthreads();
    }
    #pragma unroll
    for (int r = 0; r < 4; ++r) {
        int gr = row0 + ty * 4 + r;
        if (gr >= NPIX) continue;
        #pragma unroll
        for (int c = 0; c < 4; ++c) {
            int gc = col0 + tx * 4 + c;
            float v = acc[r][c] + bias[gc];
            v = 0.5f * v * (1.f + erff(v * 0.70710678118654752f));
            out[(size_t)(gr + 1) * HD + gc] = v;
        }
    }
}

__global__ void cls_init(const float* __restrict__ cls, float* __restrict__ h)
{
    int t = blockIdx.x * 256 + threadIdx.x;
    if (t < HD) h[t] = cls[t];
}

__global__ void copy512(const float* __restrict__ src, float* __restrict__ dst)
{
    dst[threadIdx.x] = src[threadIdx.x];
}

// ------------------------------------------------------------------
// layernorm rows of h (19601x512) into xp (19712x512), first 111 rows zero
// ------------------------------------------------------------------
__global__ void ln_pad(const float* __restrict__ h, const float* __restrict__ g,
                       const float* __restrict__ b, float* __restrict__ xp)
{
    const int row = blockIdx.x;
    const int tid = threadIdx.x;
    float* dst = xp + (size_t)row * HD;
    if (row < PADR) { dst[tid] = 0.f; dst[tid + 256] = 0.f; return; }
    const float* src = h + (size_t)(row - PADR) * HD;
    float v0 = src[tid], v1 = src[tid + 256];
    __shared__ float red[256];
    red[tid] = v0 + v1;
    __syncthreads();
    for (int off = 128; off > 0; off >>= 1) {
        if (tid < off) red[tid] += red[tid + off];
        __syncthreads();
    }
    float mu = red[0] * (1.f / HD);
    __syncthreads();
    float d0 = v0 - mu, d1 = v1 - mu;
    red[tid] = d0 * d0 + d1 * d1;
    __syncthreads();
    for (int off = 128; off > 0; off >>= 1) {
        if (tid < off) red[tid] += red[tid + off];
        __syncthreads();
    }
    float inv = rsqrtf(red[0] * (1.f / HD) + 1e-5f);
    dst[tid]       = d0 * inv * g[tid] + b[tid];
    dst[tid + 256] = d1 * inv * g[tid + 256] + b[tid + 256];
}

// ------------------------------------------------------------------
// qkv GEMM: xp(19712x512) @ W(512x192) -> head-split qh/kh/vh [h][t][d]
// ------------------------------------------------------------------
__global__ void gemm_qkv(const float* __restrict__ Xp, const float* __restrict__ W,
                         float* __restrict__ qh, float* __restrict__ kh, float* __restrict__ vh)
{
    __shared__ __align__(16) float As[16][68];
    __shared__ __align__(16) float Bs[16][68];
    const int tid = threadIdx.x;
    const int tx = tid & 15, ty = tid >> 4;
    const int row0 = blockIdx.x * 64;
    const int col0 = blockIdx.y * 64;
    float acc[4][4] = {};
    const int ai = tid >> 2;
    const int ak = (tid & 3) * 4;
    const int bk = tid >> 4;
    const int bj = (tid & 15) * 4;
    for (int k0 = 0; k0 < HD; k0 += 16) {
        float4 av = *(const float4*)&Xp[(size_t)(row0 + ai) * HD + k0 + ak];
        As[ak + 0][ai] = av.x; As[ak + 1][ai] = av.y;
        As[ak + 2][ai] = av.z; As[ak + 3][ai] = av.w;
        *(float4*)&Bs[bk][bj] = *(const float4*)&W[(size_t)(k0 + bk) * 192 + col0 + bj];
        __syncthreads();
        #pragma unroll
        for (int k = 0; k < 16; ++k) {
            float4 a = *(const float4*)&As[k][ty * 4];
            float4 b = *(const float4*)&Bs[k][tx * 4];
            acc[0][0] += a.x * b.x; acc[0][1] += a.x * b.y; acc[0][2] += a.x * b.z; acc[0][3] += a.x * b.w;
            acc[1][0] += a.y * b.x; acc[1][1] += a.y * b.y; acc[1][2] += a.y * b.z; acc[1][3] += a.y * b.w;
            acc[2][0] += a.z * b.x; acc[2][1] += a.z * b.y; acc[2][2] += a.z * b.z; acc[2][3] += a.z * b.w;
            acc[3][0] += a.w * b.x; acc[3][1] += a.w * b.y; acc[3][2] += a.w * b.z; acc[3][3] += a.w * b.w;
        }
        __syncthreads();
    }
    float* dst; float scale;
    if (blockIdx.y == 0)      { dst = qh; scale = 0.35355339059327373f; }
    else if (blockIdx.y == 1) { dst = kh; scale = 1.f; }
    else                      { dst = vh; scale = 1.f; }
    #pragma unroll
    for (int r = 0; r < 4; ++r) {
        int gr = row0 + ty * 4 + r;
        #pragma unroll
        for (int c = 0; c < 4; ++c) {
            int lc = tx * 4 + c;
            int hh = lc >> 3, d = lc & 7;
            dst[((size_t)hh * NP + gr) * DH + d] = acc[r][c] * scale;
        }
    }
}

// ------------------------------------------------------------------
// landmark means
// ------------------------------------------------------------------
__global__ void landmarks(const float* __restrict__ qh, const float* __restrict__ kh,
                          float* __restrict__ ql, float* __restrict__ kl)
{
    int idx = blockIdx.x * 256 + threadIdx.x;
    int sel = idx >> 14;
    int rem = idx & 16383;
    int h = rem >> 11;
    int i = (rem >> 3) & 255;
    int d = rem & 7;
    const float* src = sel ? kh : qh;
    size_t base = ((size_t)h * NP + (size_t)i * 77) * DH + d;
    float s = 0.f;
    for (int j = 0; j < 77; ++j) s += src[base + (size_t)j * DH];
    (sel ? kl : ql)[((size_t)h * NL + i) * DH + d] = s * (1.f / 77.f);
}

// ------------------------------------------------------------------
// attn2 = softmax(q_l @ k_l^T)
// ------------------------------------------------------------------
__global__ void attn2_softmax(const float* __restrict__ ql, const float* __restrict__ kl,
                              float* __restrict__ a)
{
    const int i = blockIdx.x, h = blockIdx.y, j = threadIdx.x;
    __shared__ float sq[8];
    __shared__ float red[256];
    if (j < 8) sq[j] = ql[((size_t)h * NL + i) * DH + j];
    __syncthreads();
    const float* kr = kl + ((size_t)h * NL + j) * DH;
    float s = 0.f;
    #pragma unroll
    for (int d = 0; d < 8; ++d) s += sq[d] * kr[d];
    red[j] = s;
    __syncthreads();
    for (int off = 128; off > 0; off >>= 1) {
        if (j < off) red[j] = fmaxf(red[j], red[j + off]);
        __syncthreads();
    }
    float mx = red[0];
    __syncthreads();
    float e = expf(s - mx);
    red[j] = e;
    __syncthreads();
    for (int off = 128; off > 0; off >>= 1) {
        if (j < off) red[j] += red[j + off];
        __syncthreads();
    }
    a[((size_t)h * NL + i) * NL + j] = e / red[0];
}

// ------------------------------------------------------------------
// pinv init
// ------------------------------------------------------------------
__global__ void pinv_norms(const float* __restrict__ a, float* __restrict__ part)
{
    const int h = blockIdx.x & 7;
    const int mode = blockIdx.x >> 3;
    const int tid = threadIdx.x;
    const float* ah = a + (size_t)h * NL * NL;
    float s = 0.f;
    if (mode == 0) { for (int j = 0; j < NL; ++j) s += fabsf(ah[tid * NL + j]); }
    else           { for (int i = 0; i < NL; ++i) s += fabsf(ah[i * NL + tid]); }
    __shared__ float red[256];
    red[tid] = s;
    __syncthreads();
    for (int off = 128; off > 0; off >>= 1) {
        if (tid < off) red[tid] = fmaxf(red[tid], red[tid + off]);
        __syncthreads();
    }
    if (tid == 0) part[mode * 8 + h] = red[0];
}

__global__ void z0_init(const float* __restrict__ a, const float* __restrict__ part,
                        float* __restrict__ z)
{
    float s1 = part[0], s2 = part[8];
    #pragma unroll
    for (int h = 1; h < 8; ++h) { s1 = fmaxf(s1, part[h]); s2 = fmaxf(s2, part[8 + h]); }
    float inv = 1.f / (s1 * s2);
    int idx = blockIdx.x * 256 + threadIdx.x;
    int h = idx >> 16;
    int rem = idx & 65535;
    int i = rem >> 8, j = rem & 255;
    z[idx] = a[((size_t)h * NL + j) * NL + i] * inv;
}

// ------------------------------------------------------------------
// batched 256x256x256: D = alpha*(A@B) + beta*A
// ------------------------------------------------------------------
__global__ void mm256(const float* __restrict__ A, const float* __restrict__ B,
                      float* __restrict__ D, float alpha, float beta)
{
    const int h = blockIdx.z;
    const float* Ah = A + (size_t)h * NL * NL;
    const float* Bh = B + (size_t)h * NL * NL;
    float* Dh = D + (size_t)h * NL * NL;
    __shared__ __align__(16) float As[16][68];
    __shared__ __align__(16) float Bs[16][68];
    const int tid = threadIdx.x;
    const int tx = tid & 15, ty = tid >> 4;
    const int row0 = blockIdx.x * 64;
    const int col0 = blockIdx.y * 64;
    float acc[4][4] = {};
    const int ai = tid >> 2;
    const int ak = (tid & 3) * 4;
    const int bk = tid >> 4;
    const int bj = (tid & 15) * 4;
    for (int k0 = 0; k0 < NL; k0 += 16) {
        float4 av = *(const float4*)&Ah[(size_t)(row0 + ai) * NL + k0 + ak];
        As[ak + 0][ai] = av.x; As[ak + 1][ai] = av.y;
        As[ak + 2][ai] = av.z; As[ak + 3][ai] = av.w;
        *(float4*)&Bs[bk][bj] = *(const float4*)&Bh[(size_t)(k0 + bk) * NL + col0 + bj];
        __syncthreads();
        #pragma unroll
        for (int k = 0; k < 16; ++k) {
            float4 a = *(const float4*)&As[k][ty * 4];
            float4 b = *(const float4*)&Bs[k][tx * 4];
            acc[0][0] += a.x * b.x; acc[0][1] += a.x * b.y; acc[0][2] += a.x * b.z; acc[0][3] += a.x * b.w;
            acc[1][0] += a.y * b.x; acc[1][1] += a.y * b.y; acc[1][2] += a.y * b.z; acc[1][3] += a.y * b.w;
            acc[2][0] += a.z * b.x; acc[2][1] += a.z * b.y; acc[2][2] += a.z * b.z; acc[2][3] += a.z * b.w;
            acc[3][0] += a.w * b.x; acc[3][1] += a.w * b.y; acc[3][2] += a.w * b.z; acc[3][3] += a.w * b.w;
        }
        __syncthreads();
    }
    #pragma unroll
    for (int r = 0; r < 4; ++r) {
        int gr = row0 + ty * 4 + r;
        #pragma unroll
        for (int c = 0; c < 4; ++c) {
            int gc = col0 + tx * 4 + c;
            Dh[(size_t)gr * NL + gc] = alpha * acc[r][c] + beta * Ah[(size_t)gr * NL + gc];
        }
    }
}

// ------------------------------------------------------------------
// attn3 @ v — online softmax, one pass
// ------------------------------------------------------------------
__global__ void attn3v(const float* __restrict__ kh, const float* __restrict__ vh,
                       const float* __restrict__ ql, float* __restrict__ wbuf)
{
    const int i = blockIdx.x, h = blockIdx.y, tid = threadIdx.x;
    __shared__ float sq[8];
    __shared__ float red[256];
    __shared__ float wpart[4][9];
    if (tid < 8) sq[tid] = ql[((size_t)h * NL + i) * DH + tid];
    __syncthreads();
    float4 q0 = *(const float4*)&sq[0];
    float4 q1 = *(const float4*)&sq[4];
    const float* kb = kh + (size_t)h * NP * DH;
    const float* vb = vh + (size_t)h * NP * DH;
    float m = -1e30f, den = 0.f;
    float4 acc0 = make_float4(0.f, 0.f, 0.f, 0.f);
    float4 acc1 = make_float4(0.f, 0.f, 0.f, 0.f);
    for (int t = tid; t < NP; t += 256) {
        const float4 k0 = *(const float4*)&kb[(size_t)t * 8];
        const float4 k1 = *(const float4*)&kb[(size_t)t * 8 + 4];
        float s = q0.x * k0.x + q0.y * k0.y + q0.z * k0.z + q0.w * k0.w
                + q1.x * k1.x + q1.y * k1.y + q1.z * k1.z + q1.w * k1.w;
        if (s > m) {
            float c = expf(m - s);
            den *= c; F4SCALE(acc0, c); F4SCALE(acc1, c);
            m = s;
        }
        float e = expf(s - m);
        den += e;
        const float4 v0 = *(const float4*)&vb[(size_t)t * 8];
        const float4 v1 = *(const float4*)&vb[(size_t)t * 8 + 4];
        F4MAD(acc0, e, v0); F4MAD(acc1, e, v1);
    }
    red[tid] = m;
    __syncthreads();
    for (int off = 128; off > 0; off >>= 1) {
        if (tid < off) red[tid] = fmaxf(red[tid], red[tid + off]);
        __syncthreads();
    }
    float M = red[0];
    float f = expf(m - M);
    den *= f; F4SCALE(acc0, f); F4SCALE(acc1, f);
    float acc[8] = {acc0.x, acc0.y, acc0.z, acc0.w, acc1.x, acc1.y, acc1.z, acc1.w};
    #pragma unroll
    for (int off = 32; off > 0; off >>= 1) {
        den += __shfl_down(den, off);
        #pragma unroll
        for (int d = 0; d < 8; ++d) acc[d] += __shfl_down(acc[d], off);
    }
    const int wave = tid >> 6, lane = tid & 63;
    if (lane == 0) {
        wpart[wave][0] = den;
        #pragma unroll
        for (int d = 0; d < 8; ++d) wpart[wave][1 + d] = acc[d];
    }
    __syncthreads();
    if (tid < 9) red[tid] = wpart[0][tid] + wpart[1][tid] + wpart[2][tid] + wpart[3][tid];
    __syncthreads();
    if (tid < 8) wbuf[((size_t)h * NL + i) * DH + tid] = red[1 + tid] / red[0];
}

// ------------------------------------------------------------------
// zw[h][i][d] = sum_j z[h][i][j] * w[h][j][d]
// ------------------------------------------------------------------
__global__ void zw_mul(const float* __restrict__ z, const float* __restrict__ w,
                       float* __restrict__ zw)
{
    int idx = blockIdx.x * 256 + threadIdx.x;
    int h = idx >> 11;
    int rem = idx & 2047;
    int i = rem >> 3, d = rem & 7;
    const float* zr = z + ((size_t)h * NL + i) * NL;
    const float* wb = w + (size_t)h * NL * DH + d;
    float s = 0.f;
    for (int j = 0; j < NL; ++j) s += zr[j] * wb[(size_t)j * DH];
    zw[idx] = s;
}

// ------------------------------------------------------------------
// attn1 fused + dwconv33(v)
// ------------------------------------------------------------------
__global__ void attn1_conv(const float* __restrict__ qh, const float* __restrict__ vh,
                           const float* __restrict__ klg, const float* __restrict__ zwg,
                           const float* __restrict__ rw, float* __restrict__ aout)
{
    const int h = blockIdx.y;
    __shared__ __align__(16) float kl[NL * DH];
    __shared__ __align__(16) float zw[NL * DH];
    const int tid = threadIdx.x;
    for (int q = tid; q < NL * DH; q += 256) {
        kl[q] = klg[(size_t)h * NL * DH + q];
        zw[q] = zwg[(size_t)h * NL * DH + q];
    }
    __syncthreads();
    const int r = blockIdx.x * 256 + tid;
    if (r >= NT) return;
    const int t = r + PADR;
    const float* qp = qh + ((size_t)h * NP + t) * DH;
    float4 q0 = *(const float4*)qp;
    float4 q1 = *(const float4*)(qp + 4);
    float m = -1e30f, den = 0.f;
    float4 acc0 = make_float4(0.f, 0.f, 0.f, 0.f);
    float4 acc1 = make_float4(0.f, 0.f, 0.f, 0.f);
    for (int i = 0; i < NL; ++i) {
        float4 k0 = *(const float4*)&kl[i * 8];
        float4 k1 = *(const float4*)&kl[i * 8 + 4];
        float s = q0.x * k0.x + q0.y * k0.y + q0.z * k0.z + q0.w * k0.w
                + q1.x * k1.x + q1.y * k1.y + q1.z * k1.z + q1.w * k1.w;
        if (s > m) {
            float c = expf(m - s);
            den *= c; F4SCALE(acc0, c); F4SCALE(acc1, c);
            m = s;
        }
        float e = expf(s - m);
        den += e;
        float4 z0 = *(const float4*)&zw[i * 8];
        float4 z1 = *(const float4*)&zw[i * 8 + 4];
        F4MAD(acc0, e, z0); F4MAD(acc1, e, z1);
    }
    float inv = 1.f / den;
    F4SCALE(acc0, inv); F4SCALE(acc1, inv);
    const float* vb = vh + (size_t)h * NP * DH;
    #pragma unroll
    for (int j = 0; j < 33; ++j) {
        int tp = t - 16 + j;
        if (tp >= NP) continue;
        float wv = rw[h * 33 + j];
        float4 v0 = *(const float4*)&vb[(size_t)tp * 8];
        float4 v1 = *(const float4*)&vb[(size_t)tp * 8 + 4];
        F4MAD(acc0, wv, v0); F4MAD(acc1, wv, v1);
    }
    float* op = aout + (size_t)r * 64 + h * 8;
    *(float4*)op = acc0;
    *(float4*)(op + 4) = acc1;
}

// ------------------------------------------------------------------
// out-proj + residual
// ------------------------------------------------------------------
__global__ void outproj(const float* __restrict__ aout, const float* __restrict__ W,
                        const float* __restrict__ bias, float* __restrict__ h)
{
    const int r0 = blockIdx.x * 8;
    const int tid = threadIdx.x;   // 512
    __shared__ float ao[8][64];
    {
        int rr = tid >> 6, kk = tid & 63;
        int gr = r0 + rr;
        ao[rr][kk] = (gr < NT) ? aout[(size_t)gr * 64 + kk] : 0.f;
    }
    __syncthreads();
    float acc[8] = {};
    for (int k = 0; k < 64; ++k) {
        float wv = W[(size_t)k * HD + tid];
        #pragma unroll
        for (int r = 0; r < 8; ++r) acc[r] += ao[r][k] * wv;
    }
    float bv = bias[tid];
    #pragma unroll
    for (int r = 0; r < 8; ++r) {
        int gr = r0 + r;
        if (gr < NT) h[(size_t)gr * HD + tid] += acc[r] + bv;
    }
}

// ------------------------------------------------------------------
// PPEG rebuilt: combined-weight prep, transpose to planar, LDS conv,
// transpose back (+bias).  Identity folded into center tap.
// ------------------------------------------------------------------
__global__ void ppeg_wprep(const float* __restrict__ w7, const float* __restrict__ b7,
                           const float* __restrict__ w5, const float* __restrict__ b5,
                           const float* __restrict__ w3, const float* __restrict__ b3,
                           float* __restrict__ wc, float* __restrict__ bsum)
{
    int idx = blockIdx.x * 256 + threadIdx.x;
    if (idx < HD * 49) {
        int c = idx / 49, t = idx - c * 49;
        int dy = t / 7 - 3, dx = t % 7 - 3;
        float v = w7[idx];
        if (dy >= -2 && dy <= 2 && dx >= -2 && dx <= 2) v += w5[c * 25 + (dy + 2) * 5 + (dx + 2)];
        if (dy >= -1 && dy <= 1 && dx >= -1 && dx <= 1) v += w3[c * 9 + (dy + 1) * 3 + (dx + 1)];
        if (t == 24) v += 1.f;   // identity
        wc[idx] = v;
    } else if (idx < HD * 49 + HD) {
        int c = idx - HD * 49;
        bsum[c] = b7[c] + b5[c] + b3[c];
    }
}

// [p][c] -> planar [c-local][p] for channels [ch0, ch0+CCH)
__global__ void ppeg_t1(const float* __restrict__ hin, float* __restrict__ plan, int ch0)
{
    __shared__ float tile[32][33];
    const int tx = threadIdx.x & 31, ty = threadIdx.x >> 5;  // 32x8
    const int p0 = blockIdx.x * 32;
    const int c0 = ch0 + blockIdx.y * 32;
    #pragma unroll
    for (int j = 0; j < 4; ++j) {
        int p = p0 + ty + j * 8;
        tile[ty + j * 8][tx] = (p < NPIX) ? hin[(size_t)(1 + p) * HD + c0 + tx] : 0.f;
    }
    __syncthreads();
    #pragma unroll
    for (int j = 0; j < 4; ++j) {
        int p = p0 + tx;
        int cc = ty + j * 8;
        if (p < NPIX) plan[(size_t)(blockIdx.y * 32 + cc) * NPIX + p] = tile[tx][cc];
    }
}

// one block per channel: whole padded 140x140 image in LDS, 49-tap conv,
// each thread computes 4 consecutive x outputs from 3x ds_read_b128 per tap-row
__global__ __launch_bounds__(256) void ppeg_conv(const float* __restrict__ plan,
                                                 const float* __restrict__ wc,
                                                 float* __restrict__ plan2, int ch0)
{
    __shared__ __align__(16) float img[PR * PW];
    const int tid = threadIdx.x;
    const int cl = blockIdx.x;
    for (int i = tid; i < PR * PW; i += 256) img[i] = 0.f;
    __syncthreads();
    const float* src = plan + (size_t)cl * NPIX;
    for (int i = tid; i < NPIX; i += 256) {
        int y = i / SIDE, x = i - y * SIDE;
        img[(y + 3) * PW + (x + 3)] = src[i];
    }
    const float* w = wc + (size_t)(ch0 + cl) * 49;  // uniform -> scalar loads
    float wr[49];
    #pragma unroll
    for (int t = 0; t < 49; ++t) wr[t] = w[t];
    __syncthreads();
    float* dst = plan2 + (size_t)cl * NPIX;
    for (int g = tid; g < 35 * SIDE; g += 256) {
        int y = g / 35, x0 = (g - y * 35) * 4;
        float acc0 = 0.f, acc1 = 0.f, acc2 = 0.f, acc3 = 0.f;
        #pragma unroll
        for (int a = 0; a < 7; ++a) {
            const float* row = &img[(y + a) * PW + x0];
            float4 A = *(const float4*)(row);
            float4 B = *(const float4*)(row + 4);
            float4 C = *(const float4*)(row + 8);
            float e0 = A.x, e1 = A.y, e2 = A.z, e3 = A.w;
            float e4 = B.x, e5 = B.y, e6 = B.z, e7 = B.w;
            float e8 = C.x, e9 = C.y;
            const float w0 = wr[a*7+0], w1 = wr[a*7+1], w2 = wr[a*7+2], w3v = wr[a*7+3];
            const float w4 = wr[a*7+4], w5v = wr[a*7+5], w6 = wr[a*7+6];
            acc0 += w0*e0 + w1*e1 + w2*e2 + w3v*e3 + w4*e4 + w5v*e5 + w6*e6;
            acc1 += w0*e1 + w1*e2 + w2*e3 + w3v*e4 + w4*e5 + w5v*e6 + w6*e7;
            acc2 += w0*e2 + w1*e3 + w2*e4 + w3v*e5 + w4*e6 + w5v*e7 + w6*e8;
            acc3 += w0*e3 + w1*e4 + w2*e5 + w3v*e6 + w4*e7 + w5v*e8 + w6*e9;
        }
        *(float4*)&dst[y * SIDE + x0] = make_float4(acc0, acc1, acc2, acc3);
    }
}

// planar [c-local][p] -> [1+p][c] with +bsum
__global__ void ppeg_t2(const float* __restrict__ plan2, const float* __restrict__ bsum,
                        float* __restrict__ hout, int ch0)
{
    __shared__ float tile[32][33];
    const int tx = threadIdx.x & 31, ty = threadIdx.x >> 5;
    const int p0 = blockIdx.x * 32;
    #pragma unroll
    for (int j = 0; j < 4; ++j) {
        int p = p0 + tx;
        int cc = ty + j * 8;
        tile[tx][cc] = (p < NPIX) ? plan2[(size_t)(blockIdx.y * 32 + cc) * NPIX + p] : 0.f;
    }
    __syncthreads();
    const int c0 = ch0 + blockIdx.y * 32;
    float bv = bsum[c0 + tx];
    #pragma unroll
    for (int j = 0; j < 4; ++j) {
        int p = p0 + ty + j * 8;
        if (p < NPIX) hout[(size_t)(1 + p) * HD + c0 + tx] = tile[ty + j * 8][tx] + bv;
    }
}

// ------------------------------------------------------------------
// final layernorm of row 0
// ------------------------------------------------------------------
__global__ void final_ln(const float* __restrict__ h, const float* __restrict__ g,
                         const float* __restrict__ b, float* __restrict__ out)
{
    const int tid = threadIdx.x;
    float v0 = h[tid], v1 = h[tid + 256];
    __shared__ float red[256];
    red[tid] = v0 + v1;
    __syncthreads();
    for (int off = 128; off > 0; off >>= 1) {
        if (tid < off) red[tid] += red[tid + off];
        __syncthreads();
    }
    float mu = red[0] * (1.f / HD);
    __syncthreads();
    float d0 = v0 - mu, d1 = v1 - mu;
    red[tid] = d0 * d0 + d1 * d1;
    __syncthreads();
    for (int off = 128; off > 0; off >>= 1) {
        if (tid < off) red[tid] += red[tid + off];
        __syncthreads();
    }
    float inv = rsqrtf(red[0] * (1.f / HD) + 1e-5f);
    out[tid]       = d0 * inv * g[tid] + b[tid];
    out[tid + 256] = d1 * inv * g[tid + 256] + b[tid + 256];
}

} // namespace

extern "C" void kernel_launch(void* const* d_in, const int* in_sizes, int n_in,
                              void* d_out, int out_size, void* d_ws, size_t ws_size,
                              hipStream_t stream)
{
    const float* x      = (const float*)d_in[0];
    const float* fc1_w  = (const float*)d_in[1];
    const float* fc1_b  = (const float*)d_in[2];
    const float* cls    = (const float*)d_in[3];
    const float* l1_g   = (const float*)d_in[4];
    const float* l1_bb  = (const float*)d_in[5];
    const float* l1_qkv = (const float*)d_in[6];
    const float* l1_ow  = (const float*)d_in[7];
    const float* l1_ob  = (const float*)d_in[8];
    const float* l1_rw  = (const float*)d_in[9];
    const float* l2_g   = (const float*)d_in[10];
    const float* l2_bb  = (const float*)d_in[11];
    const float* l2_qkv = (const float*)d_in[12];
    const float* l2_ow  = (const float*)d_in[13];
    const float* l2_ob  = (const float*)d_in[14];
    const float* l2_rw  = (const float*)d_in[15];
    const float* p7w    = (const float*)d_in[16];
    const float* p7b    = (const float*)d_in[17];
    const float* p5w    = (const float*)d_in[18];
    const float* p5b    = (const float*)d_in[19];
    const float* p3w    = (const float*)d_in[20];
    const float* p3b    = (const float*)d_in[21];
    const float* ng     = (const float*)d_in[22];
    const float* nb     = (const float*)d_in[23];
    float* out = (float*)d_out;

    char* ws = (char*)d_ws;
    size_t off = 0;
    auto alloc = [&](size_t bytes) {
        char* p = ws + off;
        off += (bytes + 255) & ~(size_t)255;
        return (float*)p;
    };
    float* bufA = alloc((size_t)NP * HD * 4);
    float* bufB = alloc((size_t)NP * HD * 4);
    float* qh   = alloc((size_t)NH * NP * DH * 4);
    float* kh   = alloc((size_t)NH * NP * DH * 4);
    float* vh   = alloc((size_t)NH * NP * DH * 4);
    float* aout = alloc((size_t)NP * 64 * 4);
    float* ql   = alloc((size_t)NH * NL * DH * 4);
    float* klm  = alloc((size_t)NH * NL * DH * 4);
    float* wbuf = alloc((size_t)NH * NL * DH * 4);
    float* zwb  = alloc((size_t)NH * NL * DH * 4);
    float* a2   = alloc((size_t)NH * NL * NL * 4);
    float* zb0  = alloc((size_t)NH * NL * NL * 4);
    float* zb1  = alloc((size_t)NH * NL * NL * 4);
    float* azb  = alloc((size_t)NH * NL * NL * 4);
    float* tb   = alloc((size_t)NH * NL * NL * 4);
    float* ub   = alloc((size_t)NH * NL * NL * 4);
    float* part = alloc(256);
    float* plan  = alloc((size_t)CCH * NPIX * 4);   // ppeg planar chunk
    float* plan2 = alloc((size_t)CCH * NPIX * 4);
    float* wcomb = alloc((size_t)HD * 49 * 4);
    float* bsum  = alloc((size_t)HD * 4);
    (void)ws_size; (void)in_sizes; (void)n_in; (void)out_size;

    gemm_fc1<<<dim3(307, 8), 256, 0, stream>>>(x, fc1_w, fc1_b, bufA);
    cls_init<<<2, 256, 0, stream>>>(cls, bufA);

    auto attention = [&](float* hbuf, float* xp, const float* lg, const float* lb,
                         const float* qkvw, const float* ow, const float* ob,
                         const float* rw) {
        ln_pad<<<NP, 256, 0, stream>>>(hbuf, lg, lb, xp);
        gemm_qkv<<<dim3(NP / 64, 3), 256, 0, stream>>>(xp, qkvw, qh, kh, vh);
        landmarks<<<128, 256, 0, stream>>>(qh, kh, ql, klm);
        attn2_softmax<<<dim3(NL, NH), 256, 0, stream>>>(ql, klm, a2);
        pinv_norms<<<16, 256, 0, stream>>>(a2, part);
        z0_init<<<2048, 256, 0, stream>>>(a2, part, zb0);
        float* zc = zb0;
        float* zn = zb1;
        for (int it = 0; it < 6; ++it) {
            mm256<<<dim3(4, 4, 8), 256, 0, stream>>>(a2, zc, azb, 1.f, 0.f);
            mm256<<<dim3(4, 4, 8), 256, 0, stream>>>(azb, azb, tb, -1.f, 7.f);
            mm256<<<dim3(4, 4, 8), 256, 0, stream>>>(azb, tb, ub, -1.f, 15.f);
            mm256<<<dim3(4, 4, 8), 256, 0, stream>>>(zc, ub, zn, -0.25f, 3.25f);
            float* tmp = zc; zc = zn; zn = tmp;
        }
        attn3v<<<dim3(NL, NH), 256, 0, stream>>>(kh, vh, ql, wbuf);
        zw_mul<<<64, 256, 0, stream>>>(zc, wbuf, zwb);
        attn1_conv<<<dim3(77, NH), 256, 0, stream>>>(qh, vh, klm, zwb, rw, aout);
        outproj<<<(NT + 7) / 8, 512, 0, stream>>>(aout, ow, ob, hbuf);
    };

    // layer 1 attention (residual add into bufA)
    attention(bufA, bufB, l1_g, l1_bb, l1_qkv, l1_ow, l1_ob, l1_rw);

    // PPEG: bufA -> bufB (planar chunked)
    ppeg_wprep<<<(HD * 49 + HD + 255) / 256, 256, 0, stream>>>(p7w, p7b, p5w, p5b, p3w, p3b,
                                                               wcomb, bsum);
    copy512<<<1, 512, 0, stream>>>(bufA, bufB);   // cls row passthrough
    constexpr int PTILES = (NPIX + 31) / 32;      // 613
    for (int ch0 = 0; ch0 < HD; ch0 += CCH) {
        ppeg_t1<<<dim3(PTILES, CCH / 32), 256, 0, stream>>>(bufA, plan, ch0);
        ppeg_conv<<<CCH, 256, 0, stream>>>(plan, wcomb, plan2, ch0);
        ppeg_t2<<<dim3(PTILES, CCH / 32), 256, 0, stream>>>(plan2, bsum, bufB, ch0);
    }

    // layer 2 attention (residual add into bufB), xp reuses bufA
    attention(bufB, bufA, l2_g, l2_bb, l2_qkv, l2_ow, l2_ob, l2_rw);
    final_ln<<<1, 256, 0, stream>>>(bufB, ng, nb, out);
}

// Round 5
// 1542.404 us; speedup vs baseline: 2.6616x; 1.3250x over previous
//
#include <hip/hip_runtime.h>

namespace {

constexpr int NP   = 19712;   // padded tokens (Nystrom)
constexpr int NT   = 19601;   // tokens incl cls
constexpr int NPIX = 19600;   // feature tokens (140x140)
constexpr int HD   = 512;     // hidden dim
constexpr int ID   = 1024;    // input dim
constexpr int NH   = 8;       // heads
constexpr int DH   = 8;       // dim per head
constexpr int NL   = 256;     // landmarks
constexpr int PADR = 111;     // left zero-pad rows
constexpr int SIDE = 140;
constexpr int CCH  = 128;     // ppeg channel chunk
constexpr int PW   = 148;     // padded image row stride (floats)

typedef __attribute__((ext_vector_type(8))) short bf16x8;
typedef __attribute__((ext_vector_type(4))) float f32x4;

#define F4MAD(a, s, v) { (a).x += (s)*(v).x; (a).y += (s)*(v).y; (a).z += (s)*(v).z; (a).w += (s)*(v).w; }
#define F4SCALE(a, s)  { (a).x *= (s); (a).y *= (s); (a).z *= (s); (a).w *= (s); }

__device__ inline short f2bf(float f) {
    union { float f; unsigned u; } v; v.f = f;
    unsigned r = v.u + 0x7fffu + ((v.u >> 16) & 1u);
    return (short)(r >> 16);
}

// ------------------------------------------------------------------
// cast+transpose: dst[c][r] = bf16(src[r][c]); grid (C/32, R/32), 256 thr
// ------------------------------------------------------------------
__global__ void castT(const float* __restrict__ src, short* __restrict__ dst, int R, int C)
{
    __shared__ float t[32][33];
    const int tx = threadIdx.x & 31, ty = threadIdx.x >> 5;
    const int c0 = blockIdx.x * 32, r0 = blockIdx.y * 32;
    #pragma unroll
    for (int j = 0; j < 4; ++j)
        t[ty + 8 * j][tx] = src[(size_t)(r0 + ty + 8 * j) * C + c0 + tx];
    __syncthreads();
    #pragma unroll
    for (int j = 0; j < 4; ++j)
        dst[(size_t)(c0 + ty + 8 * j) * R + r0 + tx] = f2bf(t[tx][ty + 8 * j]);
}

// ------------------------------------------------------------------
// fc1 MFMA: out[1+m][n] = gelu(X[m] @ W[:,n] + b[n]); M=19600 K=1024 N=512
// X fp32 (in-register cvt), Wt bf16 [n][k]. 128x128 tile, 4 waves 2x2.
// A-frag k = quad*8+j spans the full 32-wide K-step -> ONE mfma pass/step.
// ------------------------------------------------------------------
__global__ __launch_bounds__(256) void gemm_fc1(const float* __restrict__ X,
                                                const short* __restrict__ Wt,
                                                const float* __restrict__ bias,
                                                float* __restrict__ out)
{
    __shared__ __align__(16) short As[128 * 40];   // [m][k] stride 40
    __shared__ __align__(16) short Bs[128 * 40];   // [n][k] stride 40
    const int tid  = threadIdx.x;
    const int row0 = blockIdx.x * 128;
    const int col0 = blockIdx.y * 128;
    const int wave = tid >> 6, lane = tid & 63;
    const int quad = lane >> 4, l16 = lane & 15;
    const int m_off = (wave >> 1) * 64, n_off = (wave & 1) * 64;
    f32x4 acc[4][4] = {};
    for (int k0 = 0; k0 < ID; k0 += 32) {
        #pragma unroll
        for (int seg = 0; seg < 2; ++seg) {
            int lin = tid + 256 * seg;
            int row = lin >> 2, kc = (lin & 3) * 8;
            int gr = row0 + row;
            float4 x0 = make_float4(0.f, 0.f, 0.f, 0.f), x1 = x0;
            if (gr < NPIX) {
                x0 = *(const float4*)&X[(size_t)gr * ID + k0 + kc];
                x1 = *(const float4*)&X[(size_t)gr * ID + k0 + kc + 4];
            }
            bf16x8 pa;
            pa[0] = f2bf(x0.x); pa[1] = f2bf(x0.y); pa[2] = f2bf(x0.z); pa[3] = f2bf(x0.w);
            pa[4] = f2bf(x1.x); pa[5] = f2bf(x1.y); pa[6] = f2bf(x1.z); pa[7] = f2bf(x1.w);
            *(bf16x8*)&As[row * 40 + kc] = pa;
            *(bf16x8*)&Bs[row * 40 + kc] =
                *(const bf16x8*)&Wt[(size_t)(col0 + row) * ID + k0 + kc];
        }
        __syncthreads();
        bf16x8 af[4], bf[4];
        #pragma unroll
        for (int i = 0; i < 4; ++i) {
            af[i] = *(const bf16x8*)&As[(m_off + i * 16 + l16) * 40 + quad * 8];
            bf[i] = *(const bf16x8*)&Bs[(n_off + i * 16 + l16) * 40 + quad * 8];
        }
        #pragma unroll
        for (int mi = 0; mi < 4; ++mi)
            #pragma unroll
            for (int ni = 0; ni < 4; ++ni)
                acc[mi][ni] = __builtin_amdgcn_mfma_f32_16x16x32_bf16(af[mi], bf[ni], acc[mi][ni], 0, 0, 0);
        __syncthreads();
    }
    #pragma unroll
    for (int mi = 0; mi < 4; ++mi) {
        #pragma unroll
        for (int r = 0; r < 4; ++r) {
            int gr = row0 + m_off + mi * 16 + quad * 4 + r;
            if (gr >= NPIX) continue;
            #pragma unroll
            for (int ni = 0; ni < 4; ++ni) {
                int gc = col0 + n_off + ni * 16 + l16;
                float v = acc[mi][ni][r] + bias[gc];
                v = 0.5f * v * (1.f + erff(v * 0.70710678118654752f));
                out[(size_t)(gr + 1) * HD + gc] = v;
            }
        }
    }
}

// ------------------------------------------------------------------
// qkv MFMA: xp(19712x512) fp32 @ Wt(192x512 bf16) -> qh/kh/vh [h][t][d] fp32
// 128x64 tile, 4 waves (2x2: 64 rows x 32 cols each)
// ------------------------------------------------------------------
__global__ __launch_bounds__(256) void gemm_qkv(const float* __restrict__ Xp,
                                                const short* __restrict__ Wt,
                                                float* __restrict__ qh,
                                                float* __restrict__ kh,
                                                float* __restrict__ vh)
{
    __shared__ __align__(16) short As[128 * 40];
    __shared__ __align__(16) short Bs[64 * 40];
    const int tid  = threadIdx.x;
    const int row0 = blockIdx.x * 128;
    const int col0 = blockIdx.y * 64;
    const int wave = tid >> 6, lane = tid & 63;
    const int quad = lane >> 4, l16 = lane & 15;
    const int m_off = (wave >> 1) * 64, n_off = (wave & 1) * 32;
    f32x4 acc[4][2] = {};
    for (int k0 = 0; k0 < HD; k0 += 32) {
        #pragma unroll
        for (int seg = 0; seg < 2; ++seg) {
            int lin = tid + 256 * seg;
            int row = lin >> 2, kc = (lin & 3) * 8;
            float4 x0 = *(const float4*)&Xp[(size_t)(row0 + row) * HD + k0 + kc];
            float4 x1 = *(const float4*)&Xp[(size_t)(row0 + row) * HD + k0 + kc + 4];
            bf16x8 pa;
            pa[0] = f2bf(x0.x); pa[1] = f2bf(x0.y); pa[2] = f2bf(x0.z); pa[3] = f2bf(x0.w);
            pa[4] = f2bf(x1.x); pa[5] = f2bf(x1.y); pa[6] = f2bf(x1.z); pa[7] = f2bf(x1.w);
            *(bf16x8*)&As[row * 40 + kc] = pa;
        }
        {
            int nrow = tid >> 2, kc = (tid & 3) * 8;
            *(bf16x8*)&Bs[nrow * 40 + kc] =
                *(const bf16x8*)&Wt[(size_t)(col0 + nrow) * HD + k0 + kc];
        }
        __syncthreads();
        bf16x8 af[4], bf[2];
        #pragma unroll
        for (int i = 0; i < 4; ++i)
            af[i] = *(const bf16x8*)&As[(m_off + i * 16 + l16) * 40 + quad * 8];
        #pragma unroll
        for (int i = 0; i < 2; ++i)
            bf[i] = *(const bf16x8*)&Bs[(n_off + i * 16 + l16) * 40 + quad * 8];
        #pragma unroll
        for (int mi = 0; mi < 4; ++mi)
            #pragma unroll
            for (int ni = 0; ni < 2; ++ni)
                acc[mi][ni] = __builtin_amdgcn_mfma_f32_16x16x32_bf16(af[mi], bf[ni], acc[mi][ni], 0, 0, 0);
        __syncthreads();
    }
    #pragma unroll
    for (int mi = 0; mi < 4; ++mi) {
        #pragma unroll
        for (int r = 0; r < 4; ++r) {
            int gr = row0 + m_off + mi * 16 + quad * 4 + r;
            #pragma unroll
            for (int ni = 0; ni < 2; ++ni) {
                int n = col0 + n_off + ni * 16 + l16;   // 0..191
                int which = n >> 6, hh = (n >> 3) & 7, d = n & 7;
                float v = acc[mi][ni][r];
                float* dst = (which == 0) ? qh : (which == 1) ? kh : vh;
                if (which == 0) v *= 0.35355339059327373f;
                dst[((size_t)hh * NP + gr) * DH + d] = v;
            }
        }
    }
}

__global__ void cls_init(const float* __restrict__ cls, float* __restrict__ h)
{
    int t = blockIdx.x * 256 + threadIdx.x;
    if (t < HD) h[t] = cls[t];
}

__global__ void copy512(const float* __restrict__ src, float* __restrict__ dst)
{
    dst[threadIdx.x] = src[threadIdx.x];
}

// ------------------------------------------------------------------
// layernorm rows of h into xp (fp32), first 111 rows zero
// ------------------------------------------------------------------
__global__ void ln_pad(const float* __restrict__ h, const float* __restrict__ g,
                       const float* __restrict__ b, float* __restrict__ xp)
{
    const int row = blockIdx.x;
    const int tid = threadIdx.x;
    float* dst = xp + (size_t)row * HD;
    if (row < PADR) { dst[tid] = 0.f; dst[tid + 256] = 0.f; return; }
    const float* src = h + (size_t)(row - PADR) * HD;
    float v0 = src[tid], v1 = src[tid + 256];
    __shared__ float red[256];
    red[tid] = v0 + v1;
    __syncthreads();
    for (int off = 128; off > 0; off >>= 1) {
        if (tid < off) red[tid] += red[tid + off];
        __syncthreads();
    }
    float mu = red[0] * (1.f / HD);
    __syncthreads();
    float d0 = v0 - mu, d1 = v1 - mu;
    red[tid] = d0 * d0 + d1 * d1;
    __syncthreads();
    for (int off = 128; off > 0; off >>= 1) {
        if (tid < off) red[tid] += red[tid + off];
        __syncthreads();
    }
    float inv = rsqrtf(red[0] * (1.f / HD) + 1e-5f);
    dst[tid]       = d0 * inv * g[tid] + b[tid];
    dst[tid + 256] = d1 * inv * g[tid + 256] + b[tid + 256];
}

// ------------------------------------------------------------------
// landmark means
// ------------------------------------------------------------------
__global__ void landmarks(const float* __restrict__ qh, const float* __restrict__ kh,
                          float* __restrict__ ql, float* __restrict__ kl)
{
    int idx = blockIdx.x * 256 + threadIdx.x;
    int sel = idx >> 14;
    int rem = idx & 16383;
    int h = rem >> 11;
    int i = (rem >> 3) & 255;
    int d = rem & 7;
    const float* src = sel ? kh : qh;
    size_t base = ((size_t)h * NP + (size_t)i * 77) * DH + d;
    float s = 0.f;
    for (int j = 0; j < 77; ++j) s += src[base + (size_t)j * DH];
    (sel ? kl : ql)[((size_t)h * NL + i) * DH + d] = s * (1.f / 77.f);
}

// ------------------------------------------------------------------
// attn2 = softmax(q_l @ k_l^T)
// ------------------------------------------------------------------
__global__ void attn2_softmax(const float* __restrict__ ql, const float* __restrict__ kl,
                              float* __restrict__ a)
{
    const int i = blockIdx.x, h = blockIdx.y, j = threadIdx.x;
    __shared__ float sq[8];
    __shared__ float red[256];
    if (j < 8) sq[j] = ql[((size_t)h * NL + i) * DH + j];
    __syncthreads();
    const float* kr = kl + ((size_t)h * NL + j) * DH;
    float s = 0.f;
    #pragma unroll
    for (int d = 0; d < 8; ++d) s += sq[d] * kr[d];
    red[j] = s;
    __syncthreads();
    for (int off = 128; off > 0; off >>= 1) {
        if (j < off) red[j] = fmaxf(red[j], red[j + off]);
        __syncthreads();
    }
    float mx = red[0];
    __syncthreads();
    float e = expf(s - mx);
    red[j] = e;
    __syncthreads();
    for (int off = 128; off > 0; off >>= 1) {
        if (j < off) red[j] += red[j + off];
        __syncthreads();
    }
    a[((size_t)h * NL + i) * NL + j] = e / red[0];
}

// ------------------------------------------------------------------
// pinv init
// ------------------------------------------------------------------
__global__ void pinv_norms(const float* __restrict__ a, float* __restrict__ part)
{
    const int h = blockIdx.x & 7;
    const int mode = blockIdx.x >> 3;
    const int tid = threadIdx.x;
    const float* ah = a + (size_t)h * NL * NL;
    float s = 0.f;
    if (mode == 0) { for (int j = 0; j < NL; ++j) s += fabsf(ah[tid * NL + j]); }
    else           { for (int i = 0; i < NL; ++i) s += fabsf(ah[i * NL + tid]); }
    __shared__ float red[256];
    red[tid] = s;
    __syncthreads();
    for (int off = 128; off > 0; off >>= 1) {
        if (tid < off) red[tid] = fmaxf(red[tid], red[tid + off]);
        __syncthreads();
    }
    if (tid == 0) part[mode * 8 + h] = red[0];
}

__global__ void z0_init(const float* __restrict__ a, const float* __restrict__ part,
                        float* __restrict__ z)
{
    float s1 = part[0], s2 = part[8];
    #pragma unroll
    for (int h = 1; h < 8; ++h) { s1 = fmaxf(s1, part[h]); s2 = fmaxf(s2, part[8 + h]); }
    float inv = 1.f / (s1 * s2);
    int idx = blockIdx.x * 256 + threadIdx.x;
    int h = idx >> 16;
    int rem = idx & 65535;
    int i = rem >> 8, j = rem & 255;
    z[idx] = a[((size_t)h * NL + j) * NL + i] * inv;
}

// ------------------------------------------------------------------
// batched 256x256x256: D = alpha*(A@B) + beta*A   grid (8,4,8) 32x64 tiles
// ------------------------------------------------------------------
__global__ void mm256(const float* __restrict__ A, const float* __restrict__ B,
                      float* __restrict__ D, float alpha, float beta)
{
    const int h = blockIdx.z;
    const float* Ah = A + (size_t)h * NL * NL;
    const float* Bh = B + (size_t)h * NL * NL;
    float* Dh = D + (size_t)h * NL * NL;
    __shared__ __align__(16) float As[16][36];
    __shared__ __align__(16) float Bs[16][68];
    const int tid = threadIdx.x;
    const int tx = tid & 15, ty = tid >> 4;          // ty 0..15
    const int row0 = blockIdx.x * 32;
    const int col0 = blockIdx.y * 64;
    float acc[2][4] = {};
    const int ar = tid >> 3;          // 0..31
    const int ak = (tid & 7) * 2;     // 0..14
    const int bk = tid >> 4;          // 0..15
    const int bj = (tid & 15) * 4;
    for (int k0 = 0; k0 < NL; k0 += 16) {
        float2 av = *(const float2*)&Ah[(size_t)(row0 + ar) * NL + k0 + ak];
        As[ak][ar] = av.x; As[ak + 1][ar] = av.y;
        *(float4*)&Bs[bk][bj] = *(const float4*)&Bh[(size_t)(k0 + bk) * NL + col0 + bj];
        __syncthreads();
        #pragma unroll
        for (int k = 0; k < 16; ++k) {
            float2 a = *(const float2*)&As[k][ty * 2];
            float4 b = *(const float4*)&Bs[k][tx * 4];
            acc[0][0] += a.x * b.x; acc[0][1] += a.x * b.y; acc[0][2] += a.x * b.z; acc[0][3] += a.x * b.w;
            acc[1][0] += a.y * b.x; acc[1][1] += a.y * b.y; acc[1][2] += a.y * b.z; acc[1][3] += a.y * b.w;
        }
        __syncthreads();
    }
    #pragma unroll
    for (int r = 0; r < 2; ++r) {
        int gr = row0 + ty * 2 + r;
        #pragma unroll
        for (int c = 0; c < 4; ++c) {
            int gc = col0 + tx * 4 + c;
            Dh[(size_t)gr * NL + gc] = alpha * acc[r][c] + beta * Ah[(size_t)gr * NL + gc];
        }
    }
}

// ------------------------------------------------------------------
// attn3 @ v: 4 landmarks/block, branchless online softmax, shfl merge
// grid (NL/4, NH), 256 threads
// ------------------------------------------------------------------
__global__ void attn3v(const float* __restrict__ kh, const float* __restrict__ vh,
                       const float* __restrict__ ql, float* __restrict__ wbuf)
{
    const int i0 = blockIdx.x * 4, h = blockIdx.y, tid = threadIdx.x;
    __shared__ float sq[4][8];
    __shared__ float wred[4][4][10];
    if (tid < 32) sq[tid >> 3][tid & 7] = ql[((size_t)h * NL + i0 + (tid >> 3)) * DH + (tid & 7)];
    __syncthreads();
    float q[4][8];
    #pragma unroll
    for (int li = 0; li < 4; ++li)
        #pragma unroll
        for (int d = 0; d < 8; ++d) q[li][d] = sq[li][d];
    const float* kb = kh + (size_t)h * NP * DH;
    const float* vb = vh + (size_t)h * NP * DH;
    float m[4] = {-1e30f, -1e30f, -1e30f, -1e30f};
    float den[4] = {};
    float acc[4][8] = {};
    for (int t = tid; t < NP; t += 256) {
        const float4 k0 = *(const float4*)&kb[(size_t)t * 8];
        const float4 k1 = *(const float4*)&kb[(size_t)t * 8 + 4];
        const float4 v0 = *(const float4*)&vb[(size_t)t * 8];
        const float4 v1 = *(const float4*)&vb[(size_t)t * 8 + 4];
        float vv[8] = {v0.x, v0.y, v0.z, v0.w, v1.x, v1.y, v1.z, v1.w};
        float kk[8] = {k0.x, k0.y, k0.z, k0.w, k1.x, k1.y, k1.z, k1.w};
        #pragma unroll
        for (int li = 0; li < 4; ++li) {
            float s = 0.f;
            #pragma unroll
            for (int d = 0; d < 8; ++d) s += q[li][d] * kk[d];
            float nm = fmaxf(m[li], s);
            float sc = __expf(m[li] - nm);
            float e  = __expf(s - nm);
            m[li] = nm;
            den[li] = den[li] * sc + e;
            #pragma unroll
            for (int d = 0; d < 8; ++d) acc[li][d] = acc[li][d] * sc + e * vv[d];
        }
    }
    #pragma unroll
    for (int off = 1; off < 64; off <<= 1) {
        #pragma unroll
        for (int li = 0; li < 4; ++li) {
            float mo = __shfl_xor(m[li], off);
            float dn = __shfl_xor(den[li], off);
            float ao[8];
            #pragma unroll
            for (int d = 0; d < 8; ++d) ao[d] = __shfl_xor(acc[li][d], off);
            float nm = fmaxf(m[li], mo);
            float s1 = __expf(m[li] - nm), s2 = __expf(mo - nm);
            den[li] = den[li] * s1 + dn * s2;
            #pragma unroll
            for (int d = 0; d < 8; ++d) acc[li][d] = acc[li][d] * s1 + ao[d] * s2;
            m[li] = nm;
        }
    }
    const int wave = tid >> 6, lane = tid & 63;
    if (lane == 0) {
        #pragma unroll
        for (int li = 0; li < 4; ++li) {
            wred[wave][li][0] = m[li];
            wred[wave][li][1] = den[li];
            #pragma unroll
            for (int d = 0; d < 8; ++d) wred[wave][li][2 + d] = acc[li][d];
        }
    }
    __syncthreads();
    if (tid < 4) {
        const int li = tid;
        float M = wred[0][li][0], D_ = wred[0][li][1];
        float A[8];
        #pragma unroll
        for (int d = 0; d < 8; ++d) A[d] = wred[0][li][2 + d];
        #pragma unroll
        for (int w = 1; w < 4; ++w) {
            float mo = wred[w][li][0], dn = wred[w][li][1];
            float nm = fmaxf(M, mo);
            float s1 = __expf(M - nm), s2 = __expf(mo - nm);
            D_ = D_ * s1 + dn * s2;
            #pragma unroll
            for (int d = 0; d < 8; ++d) A[d] = A[d] * s1 + wred[w][li][2 + d] * s2;
            M = nm;
        }
        #pragma unroll
        for (int d = 0; d < 8; ++d)
            wbuf[((size_t)h * NL + i0 + li) * DH + d] = A[d] / D_;
    }
}

// ------------------------------------------------------------------
// zw[h][i][d] = sum_j z[h][i][j] * w[h][j][d]
// ------------------------------------------------------------------
__global__ void zw_mul(const float* __restrict__ z, const float* __restrict__ w,
                       float* __restrict__ zw)
{
    int idx = blockIdx.x * 256 + threadIdx.x;
    int h = idx >> 11;
    int rem = idx & 2047;
    int i = rem >> 3, d = rem & 7;
    const float* zr = z + ((size_t)h * NL + i) * NL;
    const float* wb = w + (size_t)h * NL * DH + d;
    float s = 0.f;
    for (int j = 0; j < NL; ++j) s += zr[j] * wb[(size_t)j * DH];
    zw[idx] = s;
}

// ------------------------------------------------------------------
// attn1 fused + dwconv33(v)
// ------------------------------------------------------------------
__global__ void attn1_conv(const float* __restrict__ qh, const float* __restrict__ vh,
                           const float* __restrict__ klg, const float* __restrict__ zwg,
                           const float* __restrict__ rw, float* __restrict__ aout)
{
    const int h = blockIdx.y;
    __shared__ __align__(16) float kl[NL * DH];
    __shared__ __align__(16) float zw[NL * DH];
    const int tid = threadIdx.x;
    for (int q = tid; q < NL * DH; q += 256) {
        kl[q] = klg[(size_t)h * NL * DH + q];
        zw[q] = zwg[(size_t)h * NL * DH + q];
    }
    __syncthreads();
    const int r = blockIdx.x * 256 + tid;
    if (r >= NT) return;
    const int t = r + PADR;
    const float* qp = qh + ((size_t)h * NP + t) * DH;
    float4 q0 = *(const float4*)qp;
    float4 q1 = *(const float4*)(qp + 4);
    float m = -1e30f, den = 0.f;
    float4 acc0 = make_float4(0.f, 0.f, 0.f, 0.f);
    float4 acc1 = make_float4(0.f, 0.f, 0.f, 0.f);
    for (int i = 0; i < NL; ++i) {
        float4 k0 = *(const float4*)&kl[i * 8];
        float4 k1 = *(const float4*)&kl[i * 8 + 4];
        float s = q0.x * k0.x + q0.y * k0.y + q0.z * k0.z + q0.w * k0.w
                + q1.x * k1.x + q1.y * k1.y + q1.z * k1.z + q1.w * k1.w;
        if (s > m) {
            float c = expf(m - s);
            den *= c; F4SCALE(acc0, c); F4SCALE(acc1, c);
            m = s;
        }
        float e = expf(s - m);
        den += e;
        float4 z0 = *(const float4*)&zw[i * 8];
        float4 z1 = *(const float4*)&zw[i * 8 + 4];
        F4MAD(acc0, e, z0); F4MAD(acc1, e, z1);
    }
    float inv = 1.f / den;
    F4SCALE(acc0, inv); F4SCALE(acc1, inv);
    const float* vb = vh + (size_t)h * NP * DH;
    #pragma unroll
    for (int j = 0; j < 33; ++j) {
        int tp = t - 16 + j;
        if (tp >= NP) continue;
        float wv = rw[h * 33 + j];
        float4 v0 = *(const float4*)&vb[(size_t)tp * 8];
        float4 v1 = *(const float4*)&vb[(size_t)tp * 8 + 4];
        F4MAD(acc0, wv, v0); F4MAD(acc1, wv, v1);
    }
    float* op = aout + (size_t)r * 64 + h * 8;
    *(float4*)op = acc0;
    *(float4*)(op + 4) = acc1;
}

// ------------------------------------------------------------------
// out-proj + residual
// ------------------------------------------------------------------
__global__ void outproj(const float* __restrict__ aout, const float* __restrict__ W,
                        const float* __restrict__ bias, float* __restrict__ h)
{
    const int r0 = blockIdx.x * 8;
    const int tid = threadIdx.x;   // 512
    __shared__ float ao[8][64];
    {
        int rr = tid >> 6, kk = tid & 63;
        int gr = r0 + rr;
        ao[rr][kk] = (gr < NT) ? aout[(size_t)gr * 64 + kk] : 0.f;
    }
    __syncthreads();
    float acc[8] = {};
    for (int k = 0; k < 64; ++k) {
        float wv = W[(size_t)k * HD + tid];
        #pragma unroll
        for (int r = 0; r < 8; ++r) acc[r] += ao[r][k] * wv;
    }
    float bv = bias[tid];
    #pragma unroll
    for (int r = 0; r < 8; ++r) {
        int gr = r0 + r;
        if (gr < NT) h[(size_t)gr * HD + tid] += acc[r] + bv;
    }
}

// ------------------------------------------------------------------
// PPEG
// ------------------------------------------------------------------
__global__ void ppeg_wprep(const float* __restrict__ w7, const float* __restrict__ b7,
                           const float* __restrict__ w5, const float* __restrict__ b5,
                           const float* __restrict__ w3, const float* __restrict__ b3,
                           float* __restrict__ wc, float* __restrict__ bsum)
{
    int idx = blockIdx.x * 256 + threadIdx.x;
    if (idx < HD * 49) {
        int c = idx / 49, t = idx - c * 49;
        int dy = t / 7 - 3, dx = t % 7 - 3;
        float v = w7[idx];
        if (dy >= -2 && dy <= 2 && dx >= -2 && dx <= 2) v += w5[c * 25 + (dy + 2) * 5 + (dx + 2)];
        if (dy >= -1 && dy <= 1 && dx >= -1 && dx <= 1) v += w3[c * 9 + (dy + 1) * 3 + (dx + 1)];
        if (t == 24) v += 1.f;
        wc[idx] = v;
    } else if (idx < HD * 49 + HD) {
        int c = idx - HD * 49;
        bsum[c] = b7[c] + b5[c] + b3[c];
    }
}

__global__ void ppeg_t1(const float* __restrict__ hin, float* __restrict__ plan, int ch0)
{
    __shared__ float tile[32][33];
    const int tx = threadIdx.x & 31, ty = threadIdx.x >> 5;
    const int p0 = blockIdx.x * 32;
    const int c0 = ch0 + blockIdx.y * 32;
    #pragma unroll
    for (int j = 0; j < 4; ++j) {
        int p = p0 + ty + j * 8;
        tile[ty + j * 8][tx] = (p < NPIX) ? hin[(size_t)(1 + p) * HD + c0 + tx] : 0.f;
    }
    __syncthreads();
    #pragma unroll
    for (int j = 0; j < 4; ++j) {
        int p = p0 + tx;
        int cc = ty + j * 8;
        if (p < NPIX) plan[(size_t)(blockIdx.y * 32 + cc) * NPIX + p] = tile[tx][cc];
    }
}

// grid (CCH, 4): y-quarter per block; 41 input rows staged in LDS
__global__ __launch_bounds__(256) void ppeg_conv(const float* __restrict__ plan,
                                                 const float* __restrict__ wc,
                                                 float* __restrict__ plan2, int ch0)
{
    __shared__ __align__(16) float img[41 * PW];
    const int tid = threadIdx.x;
    const int cl = blockIdx.x;
    const int yq = blockIdx.y;        // rows [yq*35, yq*35+35)
    for (int i = tid; i < 41 * PW; i += 256) img[i] = 0.f;
    __syncthreads();
    const float* src = plan + (size_t)cl * NPIX;
    for (int i = tid; i < 41 * SIDE; i += 256) {
        int ly = i / SIDE, x = i - ly * SIDE;
        int y = yq * 35 - 3 + ly;
        if (y >= 0 && y < SIDE) img[ly * PW + x + 3] = src[y * SIDE + x];
    }
    const float* w = wc + (size_t)(ch0 + cl) * 49;
    float wr[49];
    #pragma unroll
    for (int t = 0; t < 49; ++t) wr[t] = w[t];
    __syncthreads();
    float* dst = plan2 + (size_t)cl * NPIX;
    for (int g = tid; g < 35 * 35; g += 256) {
        int yl = g / 35, x0 = (g - yl * 35) * 4;
        float acc0 = 0.f, acc1 = 0.f, acc2 = 0.f, acc3 = 0.f;
        #pragma unroll
        for (int a = 0; a < 7; ++a) {
            const float* row = &img[(yl + a) * PW + x0];
            float4 A = *(const float4*)(row);
            float4 B = *(const float4*)(row + 4);
            float4 C = *(const float4*)(row + 8);
            float e0 = A.x, e1 = A.y, e2 = A.z, e3 = A.w;
            float e4 = B.x, e5 = B.y, e6 = B.z, e7 = B.w;
            float e8 = C.x, e9 = C.y;
            const float w0 = wr[a*7+0], w1 = wr[a*7+1], w2 = wr[a*7+2], w3v = wr[a*7+3];
            const float w4 = wr[a*7+4], w5v = wr[a*7+5], w6 = wr[a*7+6];
            acc0 += w0*e0 + w1*e1 + w2*e2 + w3v*e3 + w4*e4 + w5v*e5 + w6*e6;
            acc1 += w0*e1 + w1*e2 + w2*e3 + w3v*e4 + w4*e5 + w5v*e6 + w6*e7;
            acc2 += w0*e2 + w1*e3 + w2*e4 + w3v*e5 + w4*e6 + w5v*e7 + w6*e8;
            acc3 += w0*e3 + w1*e4 + w2*e5 + w3v*e6 + w4*e7 + w5v*e8 + w6*e9;
        }
        *(float4*)&dst[(yq * 35 + yl) * SIDE + x0] = make_float4(acc0, acc1, acc2, acc3);
    }
}

__global__ void ppeg_t2(const float* __restrict__ plan2, const float* __restrict__ bsum,
                        float* __restrict__ hout, int ch0)
{
    __shared__ float tile[32][33];
    const int tx = threadIdx.x & 31, ty = threadIdx.x >> 5;
    const int p0 = blockIdx.x * 32;
    #pragma unroll
    for (int j = 0; j < 4; ++j) {
        int p = p0 + tx;
        int cc = ty + j * 8;
        tile[tx][cc] = (p < NPIX) ? plan2[(size_t)(blockIdx.y * 32 + cc) * NPIX + p] : 0.f;
    }
    __syncthreads();
    const int c0 = ch0 + blockIdx.y * 32;
    float bv = bsum[c0 + tx];
    #pragma unroll
    for (int j = 0; j < 4; ++j) {
        int p = p0 + ty + j * 8;
        if (p < NPIX) hout[(size_t)(1 + p) * HD + c0 + tx] = tile[ty + j * 8][tx] + bv;
    }
}

// ------------------------------------------------------------------
// final layernorm of row 0
// ------------------------------------------------------------------
__global__ void final_ln(const float* __restrict__ h, const float* __restrict__ g,
                         const float* __restrict__ b, float* __restrict__ out)
{
    const int tid = threadIdx.x;
    float v0 = h[tid], v1 = h[tid + 256];
    __shared__ float red[256];
    red[tid] = v0 + v1;
    __syncthreads();
    for (int off = 128; off > 0; off >>= 1) {
        if (tid < off) red[tid] += red[tid + off];
        __syncthreads();
    }
    float mu = red[0] * (1.f / HD);
    __syncthreads();
    float d0 = v0 - mu, d1 = v1 - mu;
    red[tid] = d0 * d0 + d1 * d1;
    __syncthreads();
    for (int off = 128; off > 0; off >>= 1) {
        if (tid < off) red[tid] += red[tid + off];
        __syncthreads();
    }
    float inv = rsqrtf(red[0] * (1.f / HD) + 1e-5f);
    out[tid]       = d0 * inv * g[tid] + b[tid];
    out[tid + 256] = d1 * inv * g[tid + 256] + b[tid + 256];
}

} // namespace

extern "C" void kernel_launch(void* const* d_in, const int* in_sizes, int n_in,
                              void* d_out, int out_size, void* d_ws, size_t ws_size,
                              hipStream_t stream)
{
    const float* x      = (const float*)d_in[0];
    const float* fc1_w  = (const float*)d_in[1];
    const float* fc1_b  = (const float*)d_in[2];
    const float* cls    = (const float*)d_in[3];
    const float* l1_g   = (const float*)d_in[4];
    const float* l1_bb  = (const float*)d_in[5];
    const float* l1_qkv = (const float*)d_in[6];
    const float* l1_ow  = (const float*)d_in[7];
    const float* l1_ob  = (const float*)d_in[8];
    const float* l1_rw  = (const float*)d_in[9];
    const float* l2_g   = (const float*)d_in[10];
    const float* l2_bb  = (const float*)d_in[11];
    const float* l2_qkv = (const float*)d_in[12];
    const float* l2_ow  = (const float*)d_in[13];
    const float* l2_ob  = (const float*)d_in[14];
    const float* l2_rw  = (const float*)d_in[15];
    const float* p7w    = (const float*)d_in[16];
    const float* p7b    = (const float*)d_in[17];
    const float* p5w    = (const float*)d_in[18];
    const float* p5b    = (const float*)d_in[19];
    const float* p3w    = (const float*)d_in[20];
    const float* p3b    = (const float*)d_in[21];
    const float* ng     = (const float*)d_in[22];
    const float* nb     = (const float*)d_in[23];
    float* out = (float*)d_out;

    char* ws = (char*)d_ws;
    size_t off = 0;
    auto alloc = [&](size_t bytes) {
        char* p = ws + off;
        off += (bytes + 255) & ~(size_t)255;
        return (void*)p;
    };
    float* bufA = (float*)alloc((size_t)NP * HD * 4);
    float* bufB = (float*)alloc((size_t)NP * HD * 4);
    float* qh   = (float*)alloc((size_t)NH * NP * DH * 4);
    float* kh   = (float*)alloc((size_t)NH * NP * DH * 4);
    float* vh   = (float*)alloc((size_t)NH * NP * DH * 4);
    float* aout = (float*)alloc((size_t)NP * 64 * 4);
    float* ql   = (float*)alloc((size_t)NH * NL * DH * 4);
    float* klm  = (float*)alloc((size_t)NH * NL * DH * 4);
    float* wbuf = (float*)alloc((size_t)NH * NL * DH * 4);
    float* zwb  = (float*)alloc((size_t)NH * NL * DH * 4);
    float* a2   = (float*)alloc((size_t)NH * NL * NL * 4);
    float* zb0  = (float*)alloc((size_t)NH * NL * NL * 4);
    float* zb1  = (float*)alloc((size_t)NH * NL * NL * 4);
    float* azb  = (float*)alloc((size_t)NH * NL * NL * 4);
    float* tb   = (float*)alloc((size_t)NH * NL * NL * 4);
    float* ub   = (float*)alloc((size_t)NH * NL * NL * 4);
    float* part = (float*)alloc(256);
    float* plan  = (float*)alloc((size_t)CCH * NPIX * 4);
    float* plan2 = (float*)alloc((size_t)CCH * NPIX * 4);
    float* wcomb = (float*)alloc((size_t)HD * 49 * 4);
    float* bsum  = (float*)alloc((size_t)HD * 4);
    short* wt1   = (short*)alloc((size_t)HD * ID * 2);     // fc1_w^T bf16 [512][1024]
    short* wtq   = (short*)alloc((size_t)192 * HD * 2);    // qkv_w^T bf16 [192][512]
    (void)ws_size; (void)in_sizes; (void)n_in; (void)out_size;

    // fc1: cast/transpose weight, then MFMA GEMM + gelu
    castT<<<dim3(HD / 32, ID / 32), 256, 0, stream>>>(fc1_w, wt1, ID, HD);
    gemm_fc1<<<dim3(154, 4), 256, 0, stream>>>(x, wt1, fc1_b, bufA);
    cls_init<<<2, 256, 0, stream>>>(cls, bufA);

    auto attention = [&](float* hbuf, float* xp, const float* lg, const float* lb,
                         const float* qkvw, const float* ow, const float* ob,
                         const float* rw) {
        ln_pad<<<NP, 256, 0, stream>>>(hbuf, lg, lb, xp);
        castT<<<dim3(192 / 32, HD / 32), 256, 0, stream>>>(qkvw, wtq, HD, 192);
        gemm_qkv<<<dim3(154, 3), 256, 0, stream>>>(xp, wtq, qh, kh, vh);
        landmarks<<<128, 256, 0, stream>>>(qh, kh, ql, klm);
        attn2_softmax<<<dim3(NL, NH), 256, 0, stream>>>(ql, klm, a2);
        pinv_norms<<<16, 256, 0, stream>>>(a2, part);
        z0_init<<<2048, 256, 0, stream>>>(a2, part, zb0);
        float* zc = zb0;
        float* zn = zb1;
        for (int it = 0; it < 6; ++it) {
            mm256<<<dim3(8, 4, 8), 256, 0, stream>>>(a2, zc, azb, 1.f, 0.f);
            mm256<<<dim3(8, 4, 8), 256, 0, stream>>>(azb, azb, tb, -1.f, 7.f);
            mm256<<<dim3(8, 4, 8), 256, 0, stream>>>(azb, tb, ub, -1.f, 15.f);
            mm256<<<dim3(8, 4, 8), 256, 0, stream>>>(zc, ub, zn, -0.25f, 3.25f);
            float* tmp = zc; zc = zn; zn = tmp;
        }
        attn3v<<<dim3(NL / 4, NH), 256, 0, stream>>>(kh, vh, ql, wbuf);
        zw_mul<<<64, 256, 0, stream>>>(zc, wbuf, zwb);
        attn1_conv<<<dim3(77, NH), 256, 0, stream>>>(qh, vh, klm, zwb, rw, aout);
        outproj<<<(NT + 7) / 8, 512, 0, stream>>>(aout, ow, ob, hbuf);
    };

    attention(bufA, bufB, l1_g, l1_bb, l1_qkv, l1_ow, l1_ob, l1_rw);

    ppeg_wprep<<<(HD * 49 + HD + 255) / 256, 256, 0, stream>>>(p7w, p7b, p5w, p5b, p3w, p3b,
                                                               wcomb, bsum);
    copy512<<<1, 512, 0, stream>>>(bufA, bufB);
    constexpr int PTILES = (NPIX + 31) / 32;
    for (int ch0 = 0; ch0 < HD; ch0 += CCH) {
        ppeg_t1<<<dim3(PTILES, CCH / 32), 256, 0, stream>>>(bufA, plan, ch0);
        ppeg_conv<<<dim3(CCH, 4), 256, 0, stream>>>(plan, wcomb, plan2, ch0);
        ppeg_t2<<<dim3(PTILES, CCH / 32), 256, 0, stream>>>(plan2, bsum, bufB, ch0);
    }

    attention(bufB, bufA, l2_g, l2_bb, l2_qkv, l2_ow, l2_ob, l2_rw);
    final_ln<<<1, 256, 0, stream>>>(bufB, ng, nb, out);
}